// Round 1
// baseline (1916.698 us; speedup 1.0000x reference)
//
#include <hip/hip_runtime.h>
#include <hip/hip_bf16.h>
#include <math.h>
#include <stdint.h>

// ---- problem constants (fixed by setup_inputs) ----
#define S_LEN 4680
#define DIMSZ 1536
#define NH    12
#define HD    128
#define FRAME 1560      // 30*52
#define SP    4736      // Vt padded row length (multiple of 64, >= S_LEN)

typedef _Float16 f16;
typedef _Float16 f16x8 __attribute__((ext_vector_type(8)));
typedef _Float16 f16x4 __attribute__((ext_vector_type(4)));
typedef float    f32x4 __attribute__((ext_vector_type(4)));

// ============================================================
// f32 -> f16 cast, 4 elems/thread
// ============================================================
__global__ __launch_bounds__(256) void cast_f32_f16(const float* __restrict__ src,
                                                    f16* __restrict__ dst, int n4) {
    int i = blockIdx.x * 256 + threadIdx.x;
    if (i < n4) {
        float4 v = ((const float4*)src)[i];
        f16x4 h;
        h[0] = (f16)v.x; h[1] = (f16)v.y; h[2] = (f16)v.z; h[3] = (f16)v.w;
        ((f16x4*)dst)[i] = h;
    }
}

// ============================================================
// NT GEMM: C[M x N] = A[M x K] * B[N x K]^T + bias, all shapes 4680x1536x1536.
// A,B fp16 row-major (contiguous along K). C fp32.
// block 256 = 4 waves; wave -> 16 rows x 128 cols; block -> 64 x 128.
// grid (74, 12).
// ============================================================
__global__ __launch_bounds__(256) void gemm_nt(const f16* __restrict__ A,
                                               const f16* __restrict__ B,
                                               const float* __restrict__ bias,
                                               float* __restrict__ C) {
    const int M = S_LEN, N = DIMSZ, K = DIMSZ;
    int wave = threadIdx.x >> 6;
    int lane = threadIdx.x & 63;
    int l16  = lane & 15;
    int quad = lane >> 4;
    int m0 = blockIdx.x * 64 + wave * 16;
    int n0 = blockIdx.y * 128;

    int arow = m0 + l16; if (arow >= M) arow = M - 1;
    const f16* Ap = A + (size_t)arow * K + quad * 8;

    f32x4 acc[8] = {};
    for (int kc = 0; kc < K; kc += 32) {
        f16x8 a = *(const f16x8*)(Ap + kc);
#pragma unroll
        for (int nt = 0; nt < 8; nt++) {
            const f16* Bp = B + (size_t)(n0 + nt * 16 + l16) * K + kc + quad * 8;
            f16x8 b = *(const f16x8*)Bp;
            acc[nt] = __builtin_amdgcn_mfma_f32_16x16x32_f16(a, b, acc[nt], 0, 0, 0);
        }
    }

#pragma unroll
    for (int nt = 0; nt < 8; nt++) {
        int col = n0 + nt * 16 + l16;
        float bv = bias[col];
#pragma unroll
        for (int r = 0; r < 4; r++) {
            int row = m0 + quad * 4 + r;   // C layout: col = lane&15, row = quad*4 + reg
            if (row < M) C[(size_t)row * N + col] = acc[nt][r] + bv;
        }
    }
}

// ============================================================
// RMSNorm over 1536 + 3D RoPE, write per-head fp16 [NH][S][HD]
// grid = S, block = 256 (6 channels = 3 rope pairs per thread)
// ============================================================
__global__ __launch_bounds__(256) void norm_rope(const float* __restrict__ pre,
                                                 const float* __restrict__ g,
                                                 const float* __restrict__ freqs,
                                                 f16* __restrict__ dst) {
    int s = blockIdx.x;
    int t = threadIdx.x;
    const float* row = pre + (size_t)s * DIMSZ;

    float v[6];
    float ss = 0.f;
#pragma unroll
    for (int i = 0; i < 6; i++) { v[i] = row[t * 6 + i]; ss += v[i] * v[i]; }
#pragma unroll
    for (int off = 32; off; off >>= 1) ss += __shfl_xor(ss, off);
    __shared__ float red[4];
    if ((t & 63) == 0) red[t >> 6] = ss;
    __syncthreads();
    float tot = red[0] + red[1] + red[2] + red[3];
    float rms = rsqrtf(tot * (1.0f / DIMSZ) + 1e-6f);

    int tpos = s / FRAME;
    int rem  = s % FRAME;
    int ypos = rem / 52;
    int xpos = s % 52;

#pragma unroll
    for (int u = 0; u < 3; u++) {
        int c = t * 6 + u * 2;
        int head = c >> 7;
        int d = c & 127;
        int j = d >> 1;                       // rope channel 0..63
        int idx = (j < 22) ? tpos : ((j < 43) ? ypos : xpos);
        float ang = freqs[idx * 64 + j];
        float sn, cs;
        sincosf(ang, &sn, &cs);
        float vr = v[u * 2]     * rms * g[c];
        float vi = v[u * 2 + 1] * rms * g[c + 1];
        f16* o = dst + ((size_t)head * S_LEN + s) * HD + d;
        o[0] = (f16)(vr * cs - vi * sn);
        o[1] = (f16)(vr * sn + vi * cs);
    }
}

// ============================================================
// V cast + transpose: pre f32 [S][DIM] -> Vt fp16 [NH][HD][SP] (pad zeroed)
// ============================================================
__global__ __launch_bounds__(256) void cast_vt(const float* __restrict__ pre,
                                               f16* __restrict__ vt) {
    int i = blockIdx.x * 256 + threadIdx.x;   // over NH*HD*SP
    if (i >= NH * HD * SP) return;
    int sp = i % SP;
    int hd = i / SP;                           // head*HD + d  == column in DIM
    float val = 0.f;
    if (sp < S_LEN) val = pre[(size_t)sp * DIMSZ + hd];
    vt[i] = (f16)val;
}

// ============================================================
// Flash attention, frame-block-causal.
// grid (74, 12): (q-tile of 64, head). block 256 = 4 waves x 16 q-rows.
// Q,K fp16 [NH][S][HD]; Vt fp16 [NH][HD][SP]; O fp16 [S][DIM].
// ============================================================
__global__ __launch_bounds__(256) void attn_kernel(const f16* __restrict__ Q,
                                                   const f16* __restrict__ K,
                                                   const f16* __restrict__ Vt,
                                                   f16* __restrict__ O) {
    int head = blockIdx.y;
    int qt   = blockIdx.x;
    int wave = threadIdx.x >> 6;
    int lane = threadIdx.x & 63;
    int l16  = lane & 15;
    int quad = lane >> 4;
    int q0 = qt * 64 + wave * 16;

    __shared__ __align__(16) f16 plds[4][16][72];   // per-wave P buffer, 144B rows
    f16* pw = &plds[wave][0][0];

    // Q fragments (A layout: m = lane&15, k = quad*8+j), pre-scaled by 1/sqrt(d)
    int qrow = q0 + l16; if (qrow >= S_LEN) qrow = S_LEN - 1;
    const f16* Qp = Q + ((size_t)head * S_LEN + qrow) * HD + quad * 8;
    f16x8 aq[4];
#pragma unroll
    for (int kc = 0; kc < 4; kc++) {
        f16x8 a = *(const f16x8*)(Qp + kc * 32);
        aq[kc] = a * (f16)0.08838834764831845f;
    }

    // per-row causal limits (rows quad*4 + r)
    int limit[4];
#pragma unroll
    for (int r = 0; r < 4; r++) {
        int qp = q0 + quad * 4 + r; if (qp >= S_LEN) qp = S_LEN - 1;
        limit[r] = (qp / FRAME + 1) * FRAME;
    }
    int qlast = q0 + 15; if (qlast >= S_LEN) qlast = S_LEN - 1;
    int kv_end = (qlast / FRAME + 1) * FRAME;    // multiple of 1560

    f32x4 oacc[8] = {};
    float m_i[4], l_i[4];
#pragma unroll
    for (int r = 0; r < 4; r++) { m_i[r] = -1e30f; l_i[r] = 0.f; }

    for (int kb = 0; kb < kv_end; kb += 64) {
        // ---- scores S = Q K^T (16 x 64 per wave) ----
        f32x4 sc[4] = {};
#pragma unroll
        for (int kn = 0; kn < 4; kn++) {
            int krow = kb + kn * 16 + l16; if (krow >= S_LEN) krow = S_LEN - 1;
            const f16* Kp = K + ((size_t)head * S_LEN + krow) * HD + quad * 8;
#pragma unroll
            for (int kc = 0; kc < 4; kc++) {
                f16x8 b = *(const f16x8*)(Kp + kc * 32);
                sc[kn] = __builtin_amdgcn_mfma_f32_16x16x32_f16(aq[kc], b, sc[kn], 0, 0, 0);
            }
        }

        // ---- mask + running max ----
        float pm[4] = {-1e30f, -1e30f, -1e30f, -1e30f};
#pragma unroll
        for (int kn = 0; kn < 4; kn++) {
            int key = kb + kn * 16 + l16;
#pragma unroll
            for (int r = 0; r < 4; r++) {
                float sv = sc[kn][r];
                if (key >= limit[r]) sv = -1e30f;
                sc[kn][r] = sv;
                pm[r] = fmaxf(pm[r], sv);
            }
        }
#pragma unroll
        for (int off = 1; off < 16; off <<= 1) {
#pragma unroll
            for (int r = 0; r < 4; r++) pm[r] = fmaxf(pm[r], __shfl_xor(pm[r], off));
        }

        float alpha[4], rsum[4];
#pragma unroll
        for (int r = 0; r < 4; r++) {
            float mn = fmaxf(m_i[r], pm[r]);
            alpha[r] = __expf(m_i[r] - mn);
            m_i[r] = mn;
            rsum[r] = 0.f;
        }

        // ---- P = exp(S - m): write to LDS (C layout -> row-major) ----
#pragma unroll
        for (int kn = 0; kn < 4; kn++) {
#pragma unroll
            for (int r = 0; r < 4; r++) {
                float p = __expf(sc[kn][r] - m_i[r]);
                rsum[r] += p;
                pw[(quad * 4 + r) * 72 + kn * 16 + l16] = (f16)p;
            }
        }
#pragma unroll
        for (int off = 1; off < 16; off <<= 1) {
#pragma unroll
            for (int r = 0; r < 4; r++) rsum[r] += __shfl_xor(rsum[r], off);
        }
#pragma unroll
        for (int r = 0; r < 4; r++) l_i[r] = l_i[r] * alpha[r] + rsum[r];

        // rescale O
#pragma unroll
        for (int vn = 0; vn < 8; vn++)
#pragma unroll
            for (int r = 0; r < 4; r++) oacc[vn][r] *= alpha[r];

        // ---- read P as A fragments (wave-synchronous LDS round trip) ----
        f16x8 pa[2];
#pragma unroll
        for (int ks = 0; ks < 2; ks++)
            pa[ks] = *(const f16x8*)(pw + l16 * 72 + ks * 32 + quad * 8);

        // ---- O += P V ----
#pragma unroll
        for (int vn = 0; vn < 8; vn++) {
            const f16* Vp = Vt + ((size_t)head * HD + vn * 16 + l16) * SP + kb + quad * 8;
#pragma unroll
            for (int ks = 0; ks < 2; ks++) {
                f16x8 b = *(const f16x8*)(Vp + ks * 32);
                oacc[vn] = __builtin_amdgcn_mfma_f32_16x16x32_f16(pa[ks], b, oacc[vn], 0, 0, 0);
            }
        }
    }

    // ---- epilogue: O[row][head*128 + col] = acc / l ----
#pragma unroll
    for (int r = 0; r < 4; r++) {
        int row = q0 + quad * 4 + r;
        if (row < S_LEN) {
            float inv = 1.0f / l_i[r];
#pragma unroll
            for (int vn = 0; vn < 8; vn++) {
                O[(size_t)row * DIMSZ + head * HD + vn * 16 + l16] = (f16)(oacc[vn][r] * inv);
            }
        }
    }
}

// ============================================================
// host launch
// ============================================================
extern "C" void kernel_launch(void* const* d_in, const int* in_sizes, int n_in,
                              void* d_out, int out_size, void* d_ws, size_t ws_size,
                              hipStream_t stream) {
    const float* x     = (const float*)d_in[0];
    const float* freqs = (const float*)d_in[3];
    const float* Wq = (const float*)d_in[4];
    const float* bq = (const float*)d_in[5];
    const float* Wk = (const float*)d_in[6];
    const float* bk = (const float*)d_in[7];
    const float* Wv = (const float*)d_in[8];
    const float* bv = (const float*)d_in[9];
    const float* Wo = (const float*)d_in[10];
    const float* bo = (const float*)d_in[11];
    const float* gq = (const float*)d_in[12];
    const float* gk = (const float*)d_in[13];
    float* out = (float*)d_out;

    char* ws = (char*)d_ws;
    const size_t SZ_XH  = (size_t)S_LEN * DIMSZ * 2;       // 14,376,960
    const size_t SZ_W   = (size_t)DIMSZ * DIMSZ * 2;       //  4,718,592
    const size_t SZ_PRE = (size_t)S_LEN * DIMSZ * 4;       // 28,753,920
    const size_t SZ_QK  = SZ_XH;
    const size_t SZ_VT  = (size_t)NH * HD * SP * 2;        // 14,548,992

    f16*   xh  = (f16*)(ws);
    f16*   wqh = (f16*)(ws + SZ_XH);
    f16*   wkh = (f16*)(ws + SZ_XH + SZ_W);
    f16*   wvh = (f16*)(ws + SZ_XH + 2 * SZ_W);
    f16*   woh = (f16*)(ws + SZ_XH + 3 * SZ_W);
    float* pre = (float*)(ws + SZ_XH + 4 * SZ_W);
    f16*   Qb  = (f16*)(ws + SZ_XH + 4 * SZ_W + SZ_PRE);
    f16*   Kb  = (f16*)(ws + SZ_XH + 4 * SZ_W + SZ_PRE + SZ_QK);
    f16*   Vtb = (f16*)(ws + SZ_XH + 4 * SZ_W + SZ_PRE + 2 * SZ_QK);
    f16*   AO  = (f16*)(ws + SZ_XH + 4 * SZ_W + SZ_PRE + 2 * SZ_QK + SZ_VT);

    const int nX4 = (S_LEN * DIMSZ) / 4;      // 1,797,120
    const int nW4 = (DIMSZ * DIMSZ) / 4;      //   589,824

    cast_f32_f16<<<nX4 / 256, 256, 0, stream>>>(x,  xh,  nX4);
    cast_f32_f16<<<nW4 / 256, 256, 0, stream>>>(Wq, wqh, nW4);
    cast_f32_f16<<<nW4 / 256, 256, 0, stream>>>(Wk, wkh, nW4);
    cast_f32_f16<<<nW4 / 256, 256, 0, stream>>>(Wv, wvh, nW4);
    cast_f32_f16<<<nW4 / 256, 256, 0, stream>>>(Wo, woh, nW4);

    dim3 ggrid(74, 12);

    // Q
    gemm_nt<<<ggrid, 256, 0, stream>>>(xh, wqh, bq, pre);
    norm_rope<<<S_LEN, 256, 0, stream>>>(pre, gq, freqs, Qb);
    // K
    gemm_nt<<<ggrid, 256, 0, stream>>>(xh, wkh, bk, pre);
    norm_rope<<<S_LEN, 256, 0, stream>>>(pre, gk, freqs, Kb);
    // V
    gemm_nt<<<ggrid, 256, 0, stream>>>(xh, wvh, bv, pre);
    cast_vt<<<(NH * HD * SP) / 256, 256, 0, stream>>>(pre, Vtb);

    // attention
    attn_kernel<<<dim3(74, 12), 256, 0, stream>>>(Qb, Kb, Vtb, AO);

    // output projection -> d_out (f32)
    gemm_nt<<<ggrid, 256, 0, stream>>>(AO, woh, bo, out);
}

// Round 2
// 942.687 us; speedup vs baseline: 2.0332x; 2.0332x over previous
//
#include <hip/hip_runtime.h>
#include <hip/hip_bf16.h>
#include <math.h>
#include <stdint.h>

// ---- problem constants ----
#define S_LEN 4680
#define DIMSZ 1536
#define NH    12
#define HD    128
#define FRAME 1560
#define SP    4736      // Vt padded key length
#define SQPAD 4736      // padded q rows (37*128) for partial buffers

typedef _Float16 f16;
typedef _Float16 f16x8 __attribute__((ext_vector_type(8)));
typedef _Float16 f16x4 __attribute__((ext_vector_type(4)));
typedef float    f32x4 __attribute__((ext_vector_type(4)));

__device__ __forceinline__ void async16(const void* g, void* l) {
    __builtin_amdgcn_global_load_lds((const __attribute__((address_space(1))) void*)g,
                                     (__attribute__((address_space(3))) void*)l, 16, 0, 0);
}

// ============================================================
// f32 -> f16 cast
// ============================================================
__global__ __launch_bounds__(256) void cast_f32_f16(const float* __restrict__ src,
                                                    f16* __restrict__ dst, int n4) {
    int i = blockIdx.x * 256 + threadIdx.x;
    if (i < n4) {
        float4 v = ((const float4*)src)[i];
        f16x4 h;
        h[0] = (f16)v.x; h[1] = (f16)v.y; h[2] = (f16)v.z; h[3] = (f16)v.w;
        ((f16x4*)dst)[i] = h;
    }
}

// ============================================================
// NT GEMM: C[M x N] = A * B^T + bias. Wave: 32 rows x 64 cols.
// Block 256 = 4 waves stacked in M -> 128 x 64. grid (37, 24).
// ============================================================
__global__ __launch_bounds__(256) void gemm_f32(const f16* __restrict__ A,
                                                const f16* __restrict__ B,
                                                const float* __restrict__ bias,
                                                float* __restrict__ C) {
    int lane = threadIdx.x & 63, wv = threadIdx.x >> 6;
    int l16 = lane & 15, quad = lane >> 4;
    int m0 = blockIdx.x * 128 + wv * 32;
    int n0 = blockIdx.y * 64;

    const f16* Ap0 = A + (size_t)min(m0 + l16,      S_LEN - 1) * DIMSZ + quad * 8;
    const f16* Ap1 = A + (size_t)min(m0 + 16 + l16, S_LEN - 1) * DIMSZ + quad * 8;
    const f16* Bp  = B + (size_t)(n0 + l16) * DIMSZ + quad * 8;

    f32x4 acc[2][4] = {};
#pragma unroll 2
    for (int kc = 0; kc < DIMSZ; kc += 32) {
        f16x8 a0 = *(const f16x8*)(Ap0 + kc);
        f16x8 a1 = *(const f16x8*)(Ap1 + kc);
#pragma unroll
        for (int nt = 0; nt < 4; nt++) {
            f16x8 b = *(const f16x8*)(Bp + (size_t)nt * 16 * DIMSZ + kc);
            acc[0][nt] = __builtin_amdgcn_mfma_f32_16x16x32_f16(a0, b, acc[0][nt], 0, 0, 0);
            acc[1][nt] = __builtin_amdgcn_mfma_f32_16x16x32_f16(a1, b, acc[1][nt], 0, 0, 0);
        }
    }
#pragma unroll
    for (int mt = 0; mt < 2; mt++)
#pragma unroll
        for (int nt = 0; nt < 4; nt++) {
            int col = n0 + nt * 16 + l16;
            float bv = bias[col];
#pragma unroll
            for (int r = 0; r < 4; r++) {
                int row = m0 + mt * 16 + quad * 4 + r;
                if (row < S_LEN) C[(size_t)row * DIMSZ + col] = acc[mt][nt][r] + bv;
            }
        }
}

// ============================================================
// Same GEMM, but epilogue writes f16 transposed into Vt [col][SP]
// (kills the uncoalesced cast_vt pass entirely)
// ============================================================
__global__ __launch_bounds__(256) void gemm_vt(const f16* __restrict__ A,
                                               const f16* __restrict__ B,
                                               const float* __restrict__ bias,
                                               f16* __restrict__ Vt) {
    int lane = threadIdx.x & 63, wv = threadIdx.x >> 6;
    int l16 = lane & 15, quad = lane >> 4;
    int m0 = blockIdx.x * 128 + wv * 32;
    int n0 = blockIdx.y * 64;

    const f16* Ap0 = A + (size_t)min(m0 + l16,      S_LEN - 1) * DIMSZ + quad * 8;
    const f16* Ap1 = A + (size_t)min(m0 + 16 + l16, S_LEN - 1) * DIMSZ + quad * 8;
    const f16* Bp  = B + (size_t)(n0 + l16) * DIMSZ + quad * 8;

    f32x4 acc[2][4] = {};
#pragma unroll 2
    for (int kc = 0; kc < DIMSZ; kc += 32) {
        f16x8 a0 = *(const f16x8*)(Ap0 + kc);
        f16x8 a1 = *(const f16x8*)(Ap1 + kc);
#pragma unroll
        for (int nt = 0; nt < 4; nt++) {
            f16x8 b = *(const f16x8*)(Bp + (size_t)nt * 16 * DIMSZ + kc);
            acc[0][nt] = __builtin_amdgcn_mfma_f32_16x16x32_f16(a0, b, acc[0][nt], 0, 0, 0);
            acc[1][nt] = __builtin_amdgcn_mfma_f32_16x16x32_f16(a1, b, acc[1][nt], 0, 0, 0);
        }
    }
#pragma unroll
    for (int mt = 0; mt < 2; mt++)
#pragma unroll
        for (int nt = 0; nt < 4; nt++) {
            int col  = n0 + nt * 16 + l16;
            int base = m0 + mt * 16 + quad * 4;      // 4 consecutive rows
            if (base < S_LEN) {
                float bv = bias[col];
                f16x4 h;
#pragma unroll
                for (int r = 0; r < 4; r++) h[r] = (f16)(acc[mt][nt][r] + bv);
                *(f16x4*)(Vt + (size_t)col * SP + base) = h;   // 8B store
            }
        }
}

// ============================================================
// RMSNorm(1536) + 3D RoPE -> per-head fp16 [NH][S][HD]
// ============================================================
__global__ __launch_bounds__(256) void norm_rope(const float* __restrict__ pre,
                                                 const float* __restrict__ g,
                                                 const float* __restrict__ freqs,
                                                 f16* __restrict__ dst) {
    int s = blockIdx.x;
    int t = threadIdx.x;
    const float* row = pre + (size_t)s * DIMSZ;

    float v[6];
    float ss = 0.f;
#pragma unroll
    for (int i = 0; i < 6; i++) { v[i] = row[t * 6 + i]; ss += v[i] * v[i]; }
#pragma unroll
    for (int off = 32; off; off >>= 1) ss += __shfl_xor(ss, off);
    __shared__ float red[4];
    if ((t & 63) == 0) red[t >> 6] = ss;
    __syncthreads();
    float tot = red[0] + red[1] + red[2] + red[3];
    float rms = rsqrtf(tot * (1.0f / DIMSZ) + 1e-6f);

    int tpos = s / FRAME;
    int rem  = s % FRAME;
    int ypos = rem / 52;
    int xpos = s % 52;

#pragma unroll
    for (int u = 0; u < 3; u++) {
        int c = t * 6 + u * 2;
        int head = c >> 7;
        int d = c & 127;
        int j = d >> 1;
        int idx = (j < 22) ? tpos : ((j < 43) ? ypos : xpos);
        float ang = freqs[idx * 64 + j];
        float sn, cs;
        __sincosf(ang, &sn, &cs);
        float vr = v[u * 2]     * rms * g[c];
        float vi = v[u * 2 + 1] * rms * g[c + 1];
        f16* o = dst + ((size_t)head * S_LEN + s) * HD + d;
        o[0] = (f16)(vr * cs - vi * sn);
        o[1] = (f16)(vr * sn + vi * cs);
    }
}

// ============================================================
// Attention partials: block = (q-tile 128, head, frame-chunk).
// No online max (scores bounded; m=0). 4 waves x 32 q-rows.
// K/V tiles staged to LDS via global_load_lds w/ XOR chunk swizzle.
// grid (75, 12).
// ============================================================
__global__ __launch_bounds__(256) void attn_part(const f16* __restrict__ Q,
                                                 const f16* __restrict__ K,
                                                 const f16* __restrict__ Vt,
                                                 f16* __restrict__ Opart,
                                                 float* __restrict__ lpart) {
    int bx = blockIdx.x, head = blockIdx.y;
    int t, c;
    if (bx < 12)      { t = bx;                c = 0; }
    else if (bx < 36) { t = 12 + (bx - 12) / 2; c = (bx - 12) & 1; }
    else              { t = 24 + (bx - 36) / 3; c = (bx - 36) % 3; }

    int lane = threadIdx.x & 63, wv = threadIdx.x >> 6;
    int l16 = lane & 15, quad = lane >> 4;
    int qbase = t * 128 + wv * 32;

    __shared__ __align__(16) f16 Klds[64 * HD];    // 16KB, rows 256B, chunk-swizzled
    __shared__ __align__(16) f16 Vlds[HD * 64];    // 16KB, rows 128B, chunk-swizzled
    __shared__ __align__(16) f16 Plds[4][32][72];  // per-wave P, 144B rows

    const f16* Qh = Q  + (size_t)head * S_LEN * HD;
    const f16* Kh = K  + (size_t)head * S_LEN * HD;
    const f16* Vh = Vt + (size_t)head * HD * SP;
    f16* pw = &Plds[wv][0][0];

    // Q fragments, pre-scaled
    f16x8 aq[2][4];
#pragma unroll
    for (int mt = 0; mt < 2; mt++) {
        int qr = min(qbase + mt * 16 + l16, S_LEN - 1);
        const f16* Qp = Qh + (size_t)qr * HD + quad * 8;
#pragma unroll
        for (int kc = 0; kc < 4; kc++)
            aq[mt][kc] = (*(const f16x8*)(Qp + kc * 32)) * (f16)0.08838834764831845f;
    }

    int c0 = c * FRAME, cend = c0 + FRAME;
    int keylim[2][4];
#pragma unroll
    for (int mt = 0; mt < 2; mt++)
#pragma unroll
        for (int r = 0; r < 4; r++) {
            int qr = min(qbase + mt * 16 + quad * 4 + r, S_LEN - 1);
            keylim[mt][r] = min((qr / FRAME + 1) * FRAME, cend);
        }

    f32x4 oacc[2][8] = {};
    float lp[2][4] = {};

    for (int it = 0; it < 25; it++) {
        int kb = c0 + it * 64;
        __syncthreads();
        // ---- stage K tile (64 rows x 128 d), linear dst, swizzled src ----
#pragma unroll
        for (int i = 0; i < 4; i++) {
            int s  = i * 4 + wv;
            int ch = s * 64 + lane;
            int row = ch >> 4;
            int cc  = (ch & 15) ^ (row & 15);
            async16(Kh + (size_t)min(kb + row, S_LEN - 1) * HD + cc * 8,
                    (char*)Klds + s * 1024);
        }
        // ---- stage V tile (128 d-rows x 64 keys) ----
#pragma unroll
        for (int i = 0; i < 4; i++) {
            int s  = i * 4 + wv;
            int ch = s * 64 + lane;
            int vr = ch >> 3;
            int cc = (ch & 7) ^ (vr & 7);
            async16(Vh + (size_t)vr * SP + kb + cc * 8,
                    (char*)Vlds + s * 1024);
        }
        __builtin_amdgcn_s_waitcnt(0x0f70);   // vmcnt(0)
        __syncthreads();

        // ---- per m-tile: QK^T, exp, P->LDS ----
#pragma unroll
        for (int mt = 0; mt < 2; mt++) {
            f32x4 sc[4] = {};
#pragma unroll
            for (int kn = 0; kn < 4; kn++) {
                int krow = kn * 16 + l16;
#pragma unroll
                for (int kc = 0; kc < 4; kc++) {
                    f16x8 kf = *(const f16x8*)((const char*)Klds + krow * 256 +
                                               (((kc * 4 + quad) ^ l16) * 16));
                    sc[kn] = __builtin_amdgcn_mfma_f32_16x16x32_f16(aq[mt][kc], kf, sc[kn], 0, 0, 0);
                }
            }
#pragma unroll
            for (int kn = 0; kn < 4; kn++) {
                int key = kb + kn * 16 + l16;
#pragma unroll
                for (int r = 0; r < 4; r++) {
                    float sv = (key < keylim[mt][r]) ? sc[kn][r] : -1e30f;
                    float p = __expf(sv);
                    lp[mt][r] += p;
                    pw[(mt * 16 + quad * 4 + r) * 72 + kn * 16 + l16] = (f16)p;
                }
            }
        }

        // ---- P as A fragments ----
        f16x8 pa[2][2];
#pragma unroll
        for (int mt = 0; mt < 2; mt++)
#pragma unroll
            for (int ks = 0; ks < 2; ks++)
                pa[mt][ks] = *(const f16x8*)(pw + (mt * 16 + l16) * 72 + ks * 32 + quad * 8);

        // ---- O += P V (V frags shared across both m-tiles) ----
#pragma unroll
        for (int vn = 0; vn < 8; vn++) {
            int vrow = vn * 16 + l16;
            f16x8 v0 = *(const f16x8*)((const char*)Vlds + vrow * 128 + ((quad       ^ (l16 & 7)) * 16));
            f16x8 v1 = *(const f16x8*)((const char*)Vlds + vrow * 128 + (((4 + quad) ^ (l16 & 7)) * 16));
#pragma unroll
            for (int mt = 0; mt < 2; mt++) {
                oacc[mt][vn] = __builtin_amdgcn_mfma_f32_16x16x32_f16(pa[mt][0], v0, oacc[mt][vn], 0, 0, 0);
                oacc[mt][vn] = __builtin_amdgcn_mfma_f32_16x16x32_f16(pa[mt][1], v1, oacc[mt][vn], 0, 0, 0);
            }
        }
    }

    // ---- epilogue: normalize by chunk-l, store f16 partials ----
#pragma unroll
    for (int mt = 0; mt < 2; mt++)
#pragma unroll
        for (int r = 0; r < 4; r++) {
            float l = lp[mt][r];
#pragma unroll
            for (int off = 1; off < 16; off <<= 1) l += __shfl_xor(l, off);
            int row = qbase + mt * 16 + quad * 4 + r;
            float inv = (l > 0.f) ? 1.f / l : 0.f;
            size_t obase = ((size_t)(c * NH + head) * SQPAD + row) * HD;
#pragma unroll
            for (int vn = 0; vn < 8; vn++)
                Opart[obase + vn * 16 + l16] = (f16)(oacc[mt][vn][r] * inv);
            if (l16 == 0) lpart[(size_t)(c * NH + head) * SQPAD + row] = l;
        }
}

// ============================================================
// Combine chunk partials -> AO f16 [S][DIM]
// ============================================================
__global__ __launch_bounds__(256) void combine(const f16* __restrict__ Opart,
                                               const float* __restrict__ lpart,
                                               f16* __restrict__ AO) {
    int gid = blockIdx.x * 256 + threadIdx.x;
    if (gid >= S_LEN * NH * 16) return;
    int dc = gid & 15;
    int head = (gid >> 4) % NH;
    int q = gid / (NH * 16);
    int tt = q >> 7;
    int qlast = min(tt * 128 + 127, S_LEN - 1);
    int nf = qlast / FRAME + 1;

    float sum[8] = {};
    float ls = 0.f;
    for (int c = 0; c < nf; c++) {
        float l = lpart[(size_t)(c * NH + head) * SQPAD + q];
        if (l > 0.f) {
            f16x8 o = *(const f16x8*)(Opart + ((size_t)(c * NH + head) * SQPAD + q) * HD + dc * 8);
#pragma unroll
            for (int j = 0; j < 8; j++) sum[j] += (float)o[j] * l;
            ls += l;
        }
    }
    float inv = 1.f / ls;
    f16x8 r;
#pragma unroll
    for (int j = 0; j < 8; j++) r[j] = (f16)(sum[j] * inv);
    *(f16x8*)(AO + (size_t)q * DIMSZ + head * HD + dc * 8) = r;
}

// ============================================================
// host launch
// ============================================================
extern "C" void kernel_launch(void* const* d_in, const int* in_sizes, int n_in,
                              void* d_out, int out_size, void* d_ws, size_t ws_size,
                              hipStream_t stream) {
    const float* x     = (const float*)d_in[0];
    const float* freqs = (const float*)d_in[3];
    const float* Wq = (const float*)d_in[4];
    const float* bq = (const float*)d_in[5];
    const float* Wk = (const float*)d_in[6];
    const float* bk = (const float*)d_in[7];
    const float* Wv = (const float*)d_in[8];
    const float* bv = (const float*)d_in[9];
    const float* Wo = (const float*)d_in[10];
    const float* bo = (const float*)d_in[11];
    const float* gq = (const float*)d_in[12];
    const float* gk = (const float*)d_in[13];
    float* out = (float*)d_out;

    char* ws = (char*)d_ws;
    const size_t SZ_XH  = (size_t)S_LEN * DIMSZ * 2;             // 14,376,960
    const size_t SZ_W   = (size_t)DIMSZ * DIMSZ * 2;             //  4,718,592
    const size_t SZ_VT  = (size_t)NH * HD * SP * 2;              // 14,548,992
    const size_t SZ_OP  = (size_t)3 * NH * SQPAD * HD * 2;       // 43,646,976
    const size_t SZ_LP  = (size_t)3 * NH * SQPAD * 4;            //    681,984

    size_t off = 0;
    f16* xh  = (f16*)(ws + off); off += SZ_XH;
    f16* wqh = (f16*)(ws + off); off += SZ_W;
    f16* wkh = (f16*)(ws + off); off += SZ_W;
    f16* wvh = (f16*)(ws + off); off += SZ_W;
    f16* woh = (f16*)(ws + off); off += SZ_W;
    f16* Qb  = (f16*)(ws + off); off += SZ_XH;
    f16* Kb  = (f16*)(ws + off); off += SZ_XH;
    f16* Vtb = (f16*)(ws + off); off += SZ_VT;
    f16* AO  = (f16*)(ws + off); off += SZ_XH;
    // union region: pre (f32, Q/K pre-norm) OR Opart+lpart (attention phase)
    float* pre   = (float*)(ws + off);
    f16*   Opart = (f16*)(ws + off);
    float* lpart = (float*)(ws + off + SZ_OP);

    const int nX4 = (S_LEN * DIMSZ) / 4;
    const int nW4 = (DIMSZ * DIMSZ) / 4;

    cast_f32_f16<<<nX4 / 256, 256, 0, stream>>>(x,  xh,  nX4);
    cast_f32_f16<<<nW4 / 256, 256, 0, stream>>>(Wq, wqh, nW4);
    cast_f32_f16<<<nW4 / 256, 256, 0, stream>>>(Wk, wkh, nW4);
    cast_f32_f16<<<nW4 / 256, 256, 0, stream>>>(Wv, wvh, nW4);
    cast_f32_f16<<<nW4 / 256, 256, 0, stream>>>(Wo, woh, nW4);

    dim3 ggrid(37, 24);

    gemm_f32<<<ggrid, 256, 0, stream>>>(xh, wqh, bq, pre);
    norm_rope<<<S_LEN, 256, 0, stream>>>(pre, gq, freqs, Qb);
    gemm_f32<<<ggrid, 256, 0, stream>>>(xh, wkh, bk, pre);
    norm_rope<<<S_LEN, 256, 0, stream>>>(pre, gk, freqs, Kb);
    gemm_vt<<<ggrid, 256, 0, stream>>>(xh, wvh, bv, Vtb);

    attn_part<<<dim3(75, 12), 256, 0, stream>>>(Qb, Kb, Vtb, Opart, lpart);
    combine<<<(S_LEN * NH * 16) / 256, 256, 0, stream>>>(Opart, lpart, AO);

    gemm_f32<<<ggrid, 256, 0, stream>>>(AO, woh, bo, out);
}

// Round 4
// 567.147 us; speedup vs baseline: 3.3795x; 1.6622x over previous
//
#include <hip/hip_runtime.h>
#include <hip/hip_bf16.h>
#include <math.h>
#include <stdint.h>

// ---- problem constants ----
#define S_LEN 4680
#define DIMSZ 1536
#define NH    12
#define HD    128
#define FRAME 1560
#define SP    4736      // Vt padded key length
#define SQPAD 4736      // padded q rows for partial buffers

typedef _Float16 f16;
typedef _Float16 f16x8 __attribute__((ext_vector_type(8)));
typedef _Float16 f16x4 __attribute__((ext_vector_type(4)));
typedef __fp16   fp16x2 __attribute__((ext_vector_type(2)));
typedef float    f32x4 __attribute__((ext_vector_type(4)));

__device__ __forceinline__ void async16(const void* g, void* l) {
    __builtin_amdgcn_global_load_lds((const __attribute__((address_space(1))) void*)g,
                                     (__attribute__((address_space(3))) void*)l, 16, 0, 0);
}

union PkCast { fp16x2 v; int i; };
union FragCast { int w[4]; f16x8 v; };

// ============================================================
// f32 -> f16 cast
// ============================================================
__global__ __launch_bounds__(256) void cast_f32_f16(const float* __restrict__ src,
                                                    f16* __restrict__ dst, int n4) {
    int i = blockIdx.x * 256 + threadIdx.x;
    if (i < n4) {
        float4 v = ((const float4*)src)[i];
        f16x4 h;
        h[0] = (f16)v.x; h[1] = (f16)v.y; h[2] = (f16)v.z; h[3] = (f16)v.w;
        ((f16x4*)dst)[i] = h;
    }
}

// ============================================================
// LDS-staged NT GEMM (m97 structure): C = A * B^T + bias.
// Block 128x128, BK=64, 4 waves (2x2), wave 64x64.
// grid (37, 12). A [M][1536] f16, B [1536][1536] f16, C f32.
// ============================================================
__global__ __launch_bounds__(256) void gemm_lds(const f16* __restrict__ A,
                                                const f16* __restrict__ B,
                                                const float* __restrict__ bias,
                                                float* __restrict__ C) {
    __shared__ __align__(16) f16 Al[128 * 64];
    __shared__ __align__(16) f16 Bl[128 * 64];
    int tid = threadIdx.x;
    int lane = tid & 63, wv = tid >> 6;
    int l16 = lane & 15, quad = lane >> 4;
    int wr = (wv >> 1) * 64, wc = (wv & 1) * 64;
    int m0 = blockIdx.x * 128, n0 = blockIdx.y * 128;

    f32x4 acc[4][4] = {};

    for (int kb = 0; kb < DIMSZ; kb += 64) {
        __syncthreads();
        // stage A tile (128 rows x 64 k), XOR chunk swizzle, 4 rounds
#pragma unroll
        for (int j = 0; j < 4; j++) {
            int s = j * 256 + wv * 64 + lane;
            int r = s >> 3, cc = s & 7;
            const f16* src = A + (size_t)min(m0 + r, S_LEN - 1) * DIMSZ + kb + ((cc ^ (r & 7)) << 3);
            async16(src, (char*)Al + (j * 4096 + wv * 1024));
        }
        // stage B tile
#pragma unroll
        for (int j = 0; j < 4; j++) {
            int s = j * 256 + wv * 64 + lane;
            int r = s >> 3, cc = s & 7;
            const f16* src = B + (size_t)(n0 + r) * DIMSZ + kb + ((cc ^ (r & 7)) << 3);
            async16(src, (char*)Bl + (j * 4096 + wv * 1024));
        }
        __builtin_amdgcn_s_waitcnt(0x0f70);   // vmcnt(0)
        __syncthreads();

#pragma unroll
        for (int kc = 0; kc < 2; kc++) {
            f16x8 af[4], bf[4];
#pragma unroll
            for (int i = 0; i < 4; i++) {
                int ar = wr + i * 16 + l16;
                af[i] = *(const f16x8*)((const char*)Al + ar * 128 + (((kc * 4 + quad) ^ (ar & 7)) << 4));
                int br = wc + i * 16 + l16;
                bf[i] = *(const f16x8*)((const char*)Bl + br * 128 + (((kc * 4 + quad) ^ (br & 7)) << 4));
            }
#pragma unroll
            for (int mi = 0; mi < 4; mi++)
#pragma unroll
                for (int ni = 0; ni < 4; ni++)
                    acc[mi][ni] = __builtin_amdgcn_mfma_f32_16x16x32_f16(af[mi], bf[ni], acc[mi][ni], 0, 0, 0);
        }
    }

#pragma unroll
    for (int mi = 0; mi < 4; mi++)
#pragma unroll
        for (int ni = 0; ni < 4; ni++) {
            int col = n0 + wc + ni * 16 + l16;
            float bv = bias[col];
#pragma unroll
            for (int r = 0; r < 4; r++) {
                int row = m0 + wr + mi * 16 + quad * 4 + r;
                if (row < S_LEN) C[(size_t)row * DIMSZ + col] = acc[mi][ni][r] + bv;
            }
        }
}

// ============================================================
// Same GEMM, epilogue writes f16 transposed into Vt [col][SP]
// ============================================================
__global__ __launch_bounds__(256) void gemm_ldsvt(const f16* __restrict__ A,
                                                  const f16* __restrict__ B,
                                                  const float* __restrict__ bias,
                                                  f16* __restrict__ Vt) {
    __shared__ __align__(16) f16 Al[128 * 64];
    __shared__ __align__(16) f16 Bl[128 * 64];
    int tid = threadIdx.x;
    int lane = tid & 63, wv = tid >> 6;
    int l16 = lane & 15, quad = lane >> 4;
    int wr = (wv >> 1) * 64, wc = (wv & 1) * 64;
    int m0 = blockIdx.x * 128, n0 = blockIdx.y * 128;

    f32x4 acc[4][4] = {};

    for (int kb = 0; kb < DIMSZ; kb += 64) {
        __syncthreads();
#pragma unroll
        for (int j = 0; j < 4; j++) {
            int s = j * 256 + wv * 64 + lane;
            int r = s >> 3, cc = s & 7;
            const f16* src = A + (size_t)min(m0 + r, S_LEN - 1) * DIMSZ + kb + ((cc ^ (r & 7)) << 3);
            async16(src, (char*)Al + (j * 4096 + wv * 1024));
        }
#pragma unroll
        for (int j = 0; j < 4; j++) {
            int s = j * 256 + wv * 64 + lane;
            int r = s >> 3, cc = s & 7;
            const f16* src = B + (size_t)(n0 + r) * DIMSZ + kb + ((cc ^ (r & 7)) << 3);
            async16(src, (char*)Bl + (j * 4096 + wv * 1024));
        }
        __builtin_amdgcn_s_waitcnt(0x0f70);
        __syncthreads();

#pragma unroll
        for (int kc = 0; kc < 2; kc++) {
            f16x8 af[4], bf[4];
#pragma unroll
            for (int i = 0; i < 4; i++) {
                int ar = wr + i * 16 + l16;
                af[i] = *(const f16x8*)((const char*)Al + ar * 128 + (((kc * 4 + quad) ^ (ar & 7)) << 4));
                int br = wc + i * 16 + l16;
                bf[i] = *(const f16x8*)((const char*)Bl + br * 128 + (((kc * 4 + quad) ^ (br & 7)) << 4));
            }
#pragma unroll
            for (int mi = 0; mi < 4; mi++)
#pragma unroll
                for (int ni = 0; ni < 4; ni++)
                    acc[mi][ni] = __builtin_amdgcn_mfma_f32_16x16x32_f16(af[mi], bf[ni], acc[mi][ni], 0, 0, 0);
        }
    }

#pragma unroll
    for (int mi = 0; mi < 4; mi++)
#pragma unroll
        for (int ni = 0; ni < 4; ni++) {
            int col  = n0 + wc + ni * 16 + l16;
            int base = m0 + wr + mi * 16 + quad * 4;
            if (base < S_LEN) {
                float bv = bias[col];
                f16x4 h;
#pragma unroll
                for (int r = 0; r < 4; r++) h[r] = (f16)(acc[mi][ni][r] + bv);
                *(f16x4*)(Vt + (size_t)col * SP + base) = h;
            }
        }
}

// ============================================================
// RMSNorm(1536) + 3D RoPE -> per-head fp16 [NH][S][HD]
// ============================================================
__global__ __launch_bounds__(256) void norm_rope(const float* __restrict__ pre,
                                                 const float* __restrict__ g,
                                                 const float* __restrict__ freqs,
                                                 f16* __restrict__ dst) {
    int s = blockIdx.x;
    int t = threadIdx.x;
    const float* row = pre + (size_t)s * DIMSZ;

    float v[6];
    float ss = 0.f;
#pragma unroll
    for (int i = 0; i < 6; i++) { v[i] = row[t * 6 + i]; ss += v[i] * v[i]; }
#pragma unroll
    for (int off = 32; off; off >>= 1) ss += __shfl_xor(ss, off);
    __shared__ float red[4];
    if ((t & 63) == 0) red[t >> 6] = ss;
    __syncthreads();
    float tot = red[0] + red[1] + red[2] + red[3];
    float rms = rsqrtf(tot * (1.0f / DIMSZ) + 1e-6f);

    int tpos = s / FRAME;
    int rem  = s % FRAME;
    int ypos = rem / 52;
    int xpos = s % 52;

#pragma unroll
    for (int u = 0; u < 3; u++) {
        int c = t * 6 + u * 2;
        int head = c >> 7;
        int d = c & 127;
        int j = d >> 1;
        int idx = (j < 22) ? tpos : ((j < 43) ? ypos : xpos);
        float ang = freqs[idx * 64 + j];
        float sn, cs;
        __sincosf(ang, &sn, &cs);
        float vr = v[u * 2]     * rms * g[c];
        float vi = v[u * 2 + 1] * rms * g[c + 1];
        f16* o = dst + ((size_t)head * S_LEN + s) * HD + d;
        o[0] = (f16)(vr * cs - vi * sn);
        o[1] = (f16)(vr * sn + vi * cs);
    }
}

// ============================================================
// Attention partials, S^T formulation (S^T = K Q^T, O^T = V^T P^T).
// block = (q-tile 128, head, frame-chunk), 4 waves x 32 q.
// P C-layout -> PV B-operand via shuffles (no P LDS round trip).
// grid (75, 12).
// ============================================================
__global__ __launch_bounds__(256) void attn_part(const f16* __restrict__ Q,
                                                 const f16* __restrict__ K,
                                                 const f16* __restrict__ Vt,
                                                 f16* __restrict__ Opart,
                                                 float* __restrict__ lpart) {
    int bx = blockIdx.x, head = blockIdx.y;
    int t, c;
    if (bx < 12)      { t = bx;                 c = 0; }
    else if (bx < 36) { t = 12 + (bx - 12) / 2; c = (bx - 12) & 1; }
    else              { t = 24 + (bx - 36) / 3; c = (bx - 36) % 3; }

    int tid = threadIdx.x;
    int lane = tid & 63, wv = tid >> 6;
    int l16 = lane & 15, quad = lane >> 4;
    int qbase = t * 128 + wv * 32;

    __shared__ __align__(16) char smem[128 * 136 * 2];   // 34816 B
    f16* Klds = (f16*)smem;               // 64 rows x 128 d (16KB), chunk-swizzled
    f16* Vlds = (f16*)(smem + 16384);     // 128 d x 64 keys (16KB), chunk-swizzled
    f16* obuf = (f16*)smem;               // epilogue: [128 q][136] f16

    const f16* Qh = Q  + (size_t)head * S_LEN * HD;
    const f16* Kh = K  + (size_t)head * S_LEN * HD;
    const f16* Vh = Vt + (size_t)head * HD * SP;

    // Q fragments (B operand: n = q = l16, k = d), pre-scaled
    f16x8 aq[2][4];
    int lim[2];
    int c0 = c * FRAME, cend = c0 + FRAME;
#pragma unroll
    for (int qt = 0; qt < 2; qt++) {
        int qr = min(qbase + qt * 16 + l16, S_LEN - 1);
        const f16* Qp = Qh + (size_t)qr * HD + quad * 8;
#pragma unroll
        for (int kc = 0; kc < 4; kc++)
            aq[qt][kc] = (*(const f16x8*)(Qp + kc * 32)) * (f16)0.08838834764831845f;
        lim[qt] = min((qr / FRAME + 1) * FRAME, cend);
    }

    f32x4 oacc[2][8] = {};
    float lp[2] = {0.f, 0.f};

    int losel = ((quad & 1) * 2) * 16 + l16;
    int hisel = losel + 16;
    bool upper = (quad & 2) != 0;

    for (int it = 0; it < 25; it++) {
        int kb = c0 + it * 64;
        __syncthreads();
        // stage K tile (64 rows x 128 d)
#pragma unroll
        for (int i = 0; i < 4; i++) {
            int s  = i * 4 + wv;
            int ch = s * 64 + lane;
            int row = ch >> 4;
            int cc  = (ch & 15) ^ (row & 15);
            async16(Kh + (size_t)min(kb + row, S_LEN - 1) * HD + cc * 8,
                    (char*)Klds + s * 1024);
        }
        // stage V tile (128 d-rows x 64 keys)
#pragma unroll
        for (int i = 0; i < 4; i++) {
            int s  = i * 4 + wv;
            int ch = s * 64 + lane;
            int vr = ch >> 3;
            int cc = (ch & 7) ^ (vr & 7);
            async16(Vh + (size_t)vr * SP + kb + cc * 8,
                    (char*)Vlds + s * 1024);
        }
        __builtin_amdgcn_s_waitcnt(0x0f70);   // vmcnt(0)
        __syncthreads();

        // ---- S^T = K Q^T: A = K frag (m=key), B = Q frag (n=q) ----
        f32x4 sc[2][4] = {};
#pragma unroll
        for (int kt = 0; kt < 4; kt++) {
            int krow = kt * 16 + l16;
#pragma unroll
            for (int kc = 0; kc < 4; kc++) {
                f16x8 kf = *(const f16x8*)((const char*)Klds + krow * 256 +
                                           (((kc * 4 + quad) ^ l16) << 4));
                sc[0][kt] = __builtin_amdgcn_mfma_f32_16x16x32_f16(kf, aq[0][kc], sc[0][kt], 0, 0, 0);
                sc[1][kt] = __builtin_amdgcn_mfma_f32_16x16x32_f16(kf, aq[1][kc], sc[1][kt], 0, 0, 0);
            }
        }

        // ---- exp + mask + pack to f16 pairs ----
        int dw[2][4][2];
#pragma unroll
        for (int qt = 0; qt < 2; qt++)
#pragma unroll
            for (int kt = 0; kt < 4; kt++) {
                int keyb = kb + kt * 16 + quad * 4;
#pragma unroll
                for (int u = 0; u < 2; u++) {
                    float p0 = (keyb + 2 * u     < lim[qt]) ? __expf(sc[qt][kt][2 * u])     : 0.f;
                    float p1 = (keyb + 2 * u + 1 < lim[qt]) ? __expf(sc[qt][kt][2 * u + 1]) : 0.f;
                    lp[qt] += p0 + p1;
                    PkCast pk; pk.v = __builtin_amdgcn_cvt_pkrtz(p0, p1);
                    dw[qt][kt][u] = pk.i;
                }
            }

        // ---- C-layout -> B-operand transform via shuffles ----
        f16x8 pb[2][2];
#pragma unroll
        for (int qt = 0; qt < 2; qt++)
#pragma unroll
            for (int b0 = 0; b0 < 2; b0++) {
                int a0 = __shfl(dw[qt][2 * b0][0],     losel);
                int a1 = __shfl(dw[qt][2 * b0][1],     losel);
                int a2 = __shfl(dw[qt][2 * b0][0],     hisel);
                int a3 = __shfl(dw[qt][2 * b0][1],     hisel);
                int b0w = __shfl(dw[qt][2 * b0 + 1][0], losel);
                int b1w = __shfl(dw[qt][2 * b0 + 1][1], losel);
                int b2w = __shfl(dw[qt][2 * b0 + 1][0], hisel);
                int b3w = __shfl(dw[qt][2 * b0 + 1][1], hisel);
                FragCast fc;
                fc.w[0] = upper ? b0w : a0;
                fc.w[1] = upper ? b1w : a1;
                fc.w[2] = upper ? b2w : a2;
                fc.w[3] = upper ? b3w : a3;
                pb[qt][b0] = fc.v;
            }

        // ---- O^T += V^T P^T ----
#pragma unroll
        for (int vn = 0; vn < 8; vn++) {
            int vrow = vn * 16 + l16;
            f16x8 v0 = *(const f16x8*)((const char*)Vlds + vrow * 128 + (((quad)     ^ (vrow & 7)) << 4));
            f16x8 v1 = *(const f16x8*)((const char*)Vlds + vrow * 128 + (((4 + quad) ^ (vrow & 7)) << 4));
#pragma unroll
            for (int qt = 0; qt < 2; qt++) {
                oacc[qt][vn] = __builtin_amdgcn_mfma_f32_16x16x32_f16(v0, pb[qt][0], oacc[qt][vn], 0, 0, 0);
                oacc[qt][vn] = __builtin_amdgcn_mfma_f32_16x16x32_f16(v1, pb[qt][1], oacc[qt][vn], 0, 0, 0);
            }
        }
    }

    // ---- reduce l across quads (lanes with same l16) ----
    float inv[2];
#pragma unroll
    for (int qt = 0; qt < 2; qt++) {
        float l = lp[qt];
        l += __shfl_xor(l, 16);
        l += __shfl_xor(l, 32);
        lp[qt] = l;
        inv[qt] = 1.f / l;
    }

    __syncthreads();
    // ---- write normalized O^T into obuf as [q][d] ----
#pragma unroll
    for (int qt = 0; qt < 2; qt++) {
        int qloc = wv * 32 + qt * 16 + l16;
#pragma unroll
        for (int vn = 0; vn < 8; vn++) {
            f16x4 h;
#pragma unroll
            for (int r = 0; r < 4; r++) h[r] = (f16)(oacc[qt][vn][r] * inv[qt]);
            *(f16x4*)(obuf + qloc * 136 + vn * 16 + quad * 4) = h;
        }
        if (quad == 0) {
            int row = qbase + qt * 16 + l16;
            lpart[(size_t)(c * NH + head) * SQPAD + row] = lp[qt];
        }
    }
    __syncthreads();

    // ---- obuf -> Opart (coalesced) ----
    int qloc = tid >> 1, hh = tid & 1;
    size_t obase = ((size_t)(c * NH + head) * SQPAD + t * 128 + qloc) * HD;
#pragma unroll
    for (int p = 0; p < 8; p++) {
        int d = hh * 64 + p * 8;
        f16x8 o = *(const f16x8*)(obuf + qloc * 136 + d);
        *(f16x8*)(Opart + obase + d) = o;
    }
}

// ============================================================
// Combine chunk partials -> AO f16 [S][DIM]
// ============================================================
__global__ __launch_bounds__(256) void combine(const f16* __restrict__ Opart,
                                               const float* __restrict__ lpart,
                                               f16* __restrict__ AO) {
    int gid = blockIdx.x * 256 + threadIdx.x;
    if (gid >= S_LEN * NH * 16) return;
    int dc = gid & 15;
    int head = (gid >> 4) % NH;
    int q = gid / (NH * 16);
    int tt = q >> 7;
    int qlast = min(tt * 128 + 127, S_LEN - 1);
    int nf = qlast / FRAME + 1;

    float sum[8] = {};
    float ls = 0.f;
    for (int c = 0; c < nf; c++) {
        float l = lpart[(size_t)(c * NH + head) * SQPAD + q];
        if (l > 0.f) {
            f16x8 o = *(const f16x8*)(Opart + ((size_t)(c * NH + head) * SQPAD + q) * HD + dc * 8);
#pragma unroll
            for (int j = 0; j < 8; j++) sum[j] += (float)o[j] * l;
            ls += l;
        }
    }
    float invl = 1.f / ls;
    f16x8 r;
#pragma unroll
    for (int j = 0; j < 8; j++) r[j] = (f16)(sum[j] * invl);
    *(f16x8*)(AO + (size_t)q * DIMSZ + head * HD + dc * 8) = r;
}

// ============================================================
// host launch
// ============================================================
extern "C" void kernel_launch(void* const* d_in, const int* in_sizes, int n_in,
                              void* d_out, int out_size, void* d_ws, size_t ws_size,
                              hipStream_t stream) {
    const float* x     = (const float*)d_in[0];
    const float* freqs = (const float*)d_in[3];
    const float* Wq = (const float*)d_in[4];
    const float* bq = (const float*)d_in[5];
    const float* Wk = (const float*)d_in[6];
    const float* bk = (const float*)d_in[7];
    const float* Wv = (const float*)d_in[8];
    const float* bv = (const float*)d_in[9];
    const float* Wo = (const float*)d_in[10];
    const float* bo = (const float*)d_in[11];
    const float* gq = (const float*)d_in[12];
    const float* gk = (const float*)d_in[13];
    float* out = (float*)d_out;

    char* ws = (char*)d_ws;
    const size_t SZ_XH = (size_t)S_LEN * DIMSZ * 2;
    const size_t SZ_W  = (size_t)DIMSZ * DIMSZ * 2;
    const size_t SZ_VT = (size_t)NH * HD * SP * 2;
    const size_t SZ_OP = (size_t)3 * NH * SQPAD * HD * 2;

    size_t off = 0;
    f16* xh  = (f16*)(ws + off); off += SZ_XH;
    f16* wqh = (f16*)(ws + off); off += SZ_W;
    f16* wkh = (f16*)(ws + off); off += SZ_W;
    f16* wvh = (f16*)(ws + off); off += SZ_W;
    f16* woh = (f16*)(ws + off); off += SZ_W;
    f16* Qb  = (f16*)(ws + off); off += SZ_XH;
    f16* Kb  = (f16*)(ws + off); off += SZ_XH;
    f16* Vtb = (f16*)(ws + off); off += SZ_VT;
    f16* AO  = (f16*)(ws + off); off += SZ_XH;
    // union region: pre (f32) OR Opart+lpart
    float* pre   = (float*)(ws + off);
    f16*   Opart = (f16*)(ws + off);
    float* lpart = (float*)(ws + off + SZ_OP);

    const int nX4 = (S_LEN * DIMSZ) / 4;
    const int nW4 = (DIMSZ * DIMSZ) / 4;

    cast_f32_f16<<<nX4 / 256, 256, 0, stream>>>(x,  xh,  nX4);
    cast_f32_f16<<<nW4 / 256, 256, 0, stream>>>(Wq, wqh, nW4);
    cast_f32_f16<<<nW4 / 256, 256, 0, stream>>>(Wk, wkh, nW4);
    cast_f32_f16<<<nW4 / 256, 256, 0, stream>>>(Wv, wvh, nW4);
    cast_f32_f16<<<nW4 / 256, 256, 0, stream>>>(Wo, woh, nW4);

    dim3 ggrid(37, 12);

    gemm_lds<<<ggrid, 256, 0, stream>>>(xh, wqh, bq, pre);
    norm_rope<<<S_LEN, 256, 0, stream>>>(pre, gq, freqs, Qb);
    gemm_lds<<<ggrid, 256, 0, stream>>>(xh, wkh, bk, pre);
    norm_rope<<<S_LEN, 256, 0, stream>>>(pre, gk, freqs, Kb);
    gemm_ldsvt<<<ggrid, 256, 0, stream>>>(xh, wvh, bv, Vtb);

    attn_part<<<dim3(75, 12), 256, 0, stream>>>(Qb, Kb, Vtb, Opart, lpart);
    combine<<<(S_LEN * NH * 16) / 256, 256, 0, stream>>>(Opart, lpart, AO);

    gemm_lds<<<ggrid, 256, 0, stream>>>(AO, woh, bo, out);
}

// Round 6
// 505.561 us; speedup vs baseline: 3.7912x; 1.1218x over previous
//
#include <hip/hip_runtime.h>
#include <hip/hip_bf16.h>
#include <math.h>
#include <stdint.h>

// ---- problem constants ----
#define S_LEN 4680
#define DIMSZ 1536
#define NH    12
#define HD    128
#define FRAME 1560
#define NGRP  74        // padded 64-key/-q groups (74*64 = 4736)
#define SQPAD 4736
#define PANH  (NGRP * 8192)   // f16 elems per head in a panelized tensor

typedef _Float16 f16;
typedef _Float16 f16x8 __attribute__((ext_vector_type(8)));
typedef _Float16 f16x4 __attribute__((ext_vector_type(4)));
typedef _Float16 f16x2 __attribute__((ext_vector_type(2)));
typedef __fp16   fp16x2 __attribute__((ext_vector_type(2)));
typedef float    f32x4  __attribute__((ext_vector_type(4)));
typedef float    f32x16 __attribute__((ext_vector_type(16)));
typedef int      v2i    __attribute__((ext_vector_type(2)));

__device__ __forceinline__ void async16(const void* g, void* l) {
    __builtin_amdgcn_global_load_lds((const __attribute__((address_space(1))) void*)g,
                                     (__attribute__((address_space(3))) void*)l, 16, 0, 0);
}

union PkCast { fp16x2 v; int i; };
union FragCast { int w[4]; f16x8 v; };

// ============================================================
// all f32->f16 casts in one dispatch: y=0 x, y=1..4 weights
// ============================================================
__global__ __launch_bounds__(256) void cast_all(const float* __restrict__ x,
                                                const float* __restrict__ wq,
                                                const float* __restrict__ wk,
                                                const float* __restrict__ wv,
                                                const float* __restrict__ wo,
                                                f16* __restrict__ xh,
                                                f16* __restrict__ wh) {
    int y = blockIdx.y;
    int i = blockIdx.x * 256 + threadIdx.x;
    if (y == 0) {
        if (i < (S_LEN * DIMSZ) / 4) {
            float4 v = ((const float4*)x)[i];
            f16x4 h; h[0]=(f16)v.x; h[1]=(f16)v.y; h[2]=(f16)v.z; h[3]=(f16)v.w;
            ((f16x4*)xh)[i] = h;
        }
    } else {
        const int nW4 = (DIMSZ * DIMSZ) / 4;
        if (i < nW4) {
            const float* src = (y==1)?wq:(y==2)?wk:(y==3)?wv:wo;
            float4 v = ((const float4*)src)[i];
            f16x4 h; h[0]=(f16)v.x; h[1]=(f16)v.y; h[2]=(f16)v.z; h[3]=(f16)v.w;
            ((f16x4*)wh)[(size_t)(y-1)*nW4 + i] = h;
        }
    }
}

// ============================================================
// Fused QKV GEMM (m97 structure), grid (37,12,3).
// z=0/1: pre-norm Q/K, f16 row-major. z=2: V, f16 panelized Vt.
// Vt panels: [head][key-group][8 kchunks][128 d][8 keys]
// ============================================================
__global__ __launch_bounds__(256) void gemm_qkv(const f16* __restrict__ A,
                                                const f16* __restrict__ Bq,
                                                const f16* __restrict__ Bk,
                                                const f16* __restrict__ Bv,
                                                const float* __restrict__ bq,
                                                const float* __restrict__ bk,
                                                const float* __restrict__ bv,
                                                f16* __restrict__ preq,
                                                f16* __restrict__ prek,
                                                f16* __restrict__ vtp) {
    int z = blockIdx.z;
    const f16* B = (z==0) ? Bq : (z==1) ? Bk : Bv;
    const float* bias = (z==0) ? bq : (z==1) ? bk : bv;

    __shared__ __align__(16) f16 Al[128 * 64];
    __shared__ __align__(16) f16 Bl[128 * 64];
    int tid = threadIdx.x;
    int lane = tid & 63, wv = tid >> 6;
    int l16 = lane & 15, quad = lane >> 4;
    int wr = (wv >> 1) * 64, wc = (wv & 1) * 64;
    int m0 = blockIdx.x * 128, n0 = blockIdx.y * 128;

    f32x4 acc[4][4] = {};

    for (int kb = 0; kb < DIMSZ; kb += 64) {
        __syncthreads();
#pragma unroll
        for (int j = 0; j < 4; j++) {
            int s = j * 256 + wv * 64 + lane;
            int r = s >> 3, cc = s & 7;
            const f16* src = A + (size_t)min(m0 + r, S_LEN - 1) * DIMSZ + kb + ((cc ^ (r & 7)) << 3);
            async16(src, (char*)Al + (j * 4096 + wv * 1024));
        }
#pragma unroll
        for (int j = 0; j < 4; j++) {
            int s = j * 256 + wv * 64 + lane;
            int r = s >> 3, cc = s & 7;
            const f16* src = B + (size_t)(n0 + r) * DIMSZ + kb + ((cc ^ (r & 7)) << 3);
            async16(src, (char*)Bl + (j * 4096 + wv * 1024));
        }
        __builtin_amdgcn_s_waitcnt(0x0f70);
        __syncthreads();

#pragma unroll
        for (int kc = 0; kc < 2; kc++) {
            f16x8 af[4], bf[4];
#pragma unroll
            for (int i = 0; i < 4; i++) {
                int ar = wr + i * 16 + l16;
                af[i] = *(const f16x8*)((const char*)Al + ar * 128 + (((kc * 4 + quad) ^ (ar & 7)) << 4));
                int br = wc + i * 16 + l16;
                bf[i] = *(const f16x8*)((const char*)Bl + br * 128 + (((kc * 4 + quad) ^ (br & 7)) << 4));
            }
#pragma unroll
            for (int mi = 0; mi < 4; mi++)
#pragma unroll
                for (int ni = 0; ni < 4; ni++)
                    acc[mi][ni] = __builtin_amdgcn_mfma_f32_16x16x32_f16(af[mi], bf[ni], acc[mi][ni], 0, 0, 0);
        }
    }

    if (z < 2) {
        f16* C = (z == 0) ? preq : prek;
#pragma unroll
        for (int mi = 0; mi < 4; mi++)
#pragma unroll
            for (int ni = 0; ni < 4; ni++) {
                int col = n0 + wc + ni * 16 + l16;
                float bv_ = bias[col];
#pragma unroll
                for (int r = 0; r < 4; r++) {
                    int row = m0 + wr + mi * 16 + quad * 4 + r;
                    if (row < S_LEN) C[(size_t)row * DIMSZ + col] = (f16)(acc[mi][ni][r] + bv_);
                }
            }
    } else {
#pragma unroll
        for (int mi = 0; mi < 4; mi++)
#pragma unroll
            for (int ni = 0; ni < 4; ni++) {
                int col  = n0 + wc + ni * 16 + l16;
                int vhead = col >> 7, d = col & 127;
                int base = m0 + wr + mi * 16 + quad * 4;   // 4 consecutive keys
                if (base < S_LEN) {
                    float bv_ = bias[col];
                    f16x4 h;
#pragma unroll
                    for (int r = 0; r < 4; r++) h[r] = (f16)(acc[mi][ni][r] + bv_);
                    size_t off = (size_t)vhead * PANH + (size_t)(base >> 6) * 8192
                               + ((base >> 3) & 7) * 1024 + d * 8 + (base & 7);
                    *(f16x4*)(vtp + off) = h;
                }
            }
    }
}

// ============================================================
// RMSNorm + RoPE -> panelized Q/K: [head][q-group][16 dchunks][64 q][8 d]
// grid (S_LEN, 2): y=0 Q, y=1 K
// ============================================================
__global__ __launch_bounds__(256) void norm_rope(const f16* __restrict__ preq,
                                                 const f16* __restrict__ prek,
                                                 const float* __restrict__ gq,
                                                 const float* __restrict__ gk,
                                                 const float* __restrict__ freqs,
                                                 f16* __restrict__ Qp,
                                                 f16* __restrict__ Kp) {
    int s = blockIdx.x, which = blockIdx.y;
    int t = threadIdx.x;
    const f16* pre = which ? prek : preq;
    const float* g = which ? gk : gq;
    f16* dst = which ? Kp : Qp;
    const f16* row = pre + (size_t)s * DIMSZ + t * 6;

    float v[6];
    float ss = 0.f;
#pragma unroll
    for (int i = 0; i < 3; i++) {
        f16x2 hp = *(const f16x2*)(row + 2 * i);
        v[2*i] = (float)hp[0]; v[2*i+1] = (float)hp[1];
        ss += v[2*i]*v[2*i] + v[2*i+1]*v[2*i+1];
    }
#pragma unroll
    for (int off = 32; off; off >>= 1) ss += __shfl_xor(ss, off);
    __shared__ float red[4];
    if ((t & 63) == 0) red[t >> 6] = ss;
    __syncthreads();
    float tot = red[0] + red[1] + red[2] + red[3];
    float rms = rsqrtf(tot * (1.0f / DIMSZ) + 1e-6f);

    int tpos = s / FRAME;
    int rem  = s % FRAME;
    int ypos = rem / 52;
    int xpos = s % 52;

#pragma unroll
    for (int u = 0; u < 3; u++) {
        int c = t * 6 + u * 2;
        int head = c >> 7;
        int d = c & 127;
        int j = d >> 1;
        int idx = (j < 22) ? tpos : ((j < 43) ? ypos : xpos);
        float ang = freqs[idx * 64 + j];
        float sn, cs;
        __sincosf(ang, &sn, &cs);
        float vr = v[u * 2]     * rms * g[c];
        float vi = v[u * 2 + 1] * rms * g[c + 1];
        f16* o = dst + (size_t)head * PANH + (size_t)(s >> 6) * 8192
               + (d >> 3) * 512 + (s & 63) * 8 + (d & 7);
        o[0] = (f16)(vr * cs - vi * sn);
        o[1] = (f16)(vr * sn + vi * cs);
    }
}

// ============================================================
// Attention partials. Block = 2 waves x 64 q (128 q-tile), head, chunk.
// 32x32x16 MFMA, S^T = K Q^T, O^T = V^T P^T.
// LDS = byte-image of panelized global groups -> conflict-free reads.
// P transform via v_permlane32_swap (VALU pipe): vdst.hi32 <-> vsrc.lo32.
// grid (75, 12), block 128.
// ============================================================
__global__ __launch_bounds__(128, 2) void attn_part(const f16* __restrict__ Qp,
                                                    const f16* __restrict__ Kp,
                                                    const f16* __restrict__ Vp,
                                                    f16* __restrict__ Opart,
                                                    float* __restrict__ lpart) {
    int bx = blockIdx.x, head = blockIdx.y;
    int t, c;
    if (bx < 12)      { t = bx;                 c = 0; }
    else if (bx < 36) { t = 12 + (bx - 12) / 2; c = (bx - 12) & 1; }
    else              { t = 24 + (bx - 36) / 3; c = (bx - 36) % 3; }

    int qlast = min(t * 128 + 127, S_LEN - 1);
    int nc    = qlast / FRAME + 1;
    int kvend = nc * FRAME; if (kvend > S_LEN) kvend = S_LEN;
    int nG    = (kvend + 63) >> 6;
    int g0 = (c * nG) / nc, g1 = ((c + 1) * nG) / nc;
    int limB = ((t * 128) / FRAME + 1) * FRAME;

    int tid = threadIdx.x, lane = tid & 63, wv = tid >> 6;
    int l31 = lane & 31, lh = lane >> 5;
    int qw = t * 128 + wv * 64;

    __shared__ __align__(16) char smem[32768];
    const char* smc = smem;

    // Q B-frags from panelized global (coalesced), pre-scaled
    const f16* Qg = Qp + ((size_t)head * NGRP + (qw >> 6)) * 8192;
    f16x8 bqf[2][8];
#pragma unroll
    for (int nt = 0; nt < 2; nt++)
#pragma unroll
        for (int ks = 0; ks < 8; ks++) {
            f16x8 vq = *(const f16x8*)(Qg + (2 * ks + lh) * 512 + (l31 + 32 * nt) * 8);
            bqf[nt][ks] = vq * (f16)0.08838834764831845f;
        }

    int lim[2];
#pragma unroll
    for (int nt = 0; nt < 2; nt++) {
        int q = qw + l31 + 32 * nt;
        lim[nt] = (q / FRAME + 1) * FRAME;
    }

    f32x16 oacc[4][2] = {};
    float lp[2] = {0.f, 0.f};

    int koff = lh * 1024 + l31 * 16;
    int voff = lh * 2048 + l31 * 16;

    for (int g = g0; g < g1; g++) {
        int kb = g * 64;
        __syncthreads();
        const f16* Kg = Kp + ((size_t)head * NGRP + g) * 8192;
        const f16* Vg = Vp + ((size_t)head * NGRP + g) * 8192;
#pragma unroll
        for (int i = 0; i < 8; i++) {
            int s = i * 2 + wv;
            async16(Kg + s * 512 + lane * 8, (char*)smem + s * 1024 + lane * 16);
        }
#pragma unroll
        for (int i = 0; i < 8; i++) {
            int s = i * 2 + wv;
            async16(Vg + s * 512 + lane * 8, (char*)smem + 16384 + s * 1024 + lane * 16);
        }
        __builtin_amdgcn_s_waitcnt(0x0f70);   // vmcnt(0)
        __syncthreads();

        bool domask = (kb + 64 > limB);

#pragma unroll
        for (int kt = 0; kt < 2; kt++) {
            // ---- S^T = K Q^T ----
            f32x16 sc0 = {}, sc1 = {};
#pragma unroll
            for (int h = 0; h < 2; h++) {
                f16x8 ka[4];
#pragma unroll
                for (int i = 0; i < 4; i++)
                    ka[i] = *(const f16x8*)(smc + koff + (h * 4 + i) * 2048 + kt * 512);
#pragma unroll
                for (int i = 0; i < 4; i++) {
                    sc0 = __builtin_amdgcn_mfma_f32_32x32x16_f16(ka[i], bqf[0][h*4+i], sc0, 0, 0, 0);
                    sc1 = __builtin_amdgcn_mfma_f32_32x32x16_f16(ka[i], bqf[1][h*4+i], sc1, 0, 0, 0);
                }
            }

            // ---- mask + exp + pack ----
            int w[2][8];
            int keyb = kb + kt * 32 + 4 * lh;
#pragma unroll
            for (int nt = 0; nt < 2; nt++) {
#pragma unroll
                for (int p = 0; p < 8; p++) {
                    const int r0 = 2 * p;
                    float s0 = (nt == 0) ? sc0[r0]     : sc1[r0];
                    float s1 = (nt == 0) ? sc0[r0 + 1] : sc1[r0 + 1];
                    if (domask) {
                        int k0 = keyb + (r0 & 3) + 8 * (r0 >> 2);
                        if (k0     >= lim[nt]) s0 = -1e30f;
                        if (k0 + 1 >= lim[nt]) s1 = -1e30f;
                    }
                    float p0 = __expf(s0), p1 = __expf(s1);
                    lp[nt] += p0 + p1;
                    PkCast pk; pk.v = __builtin_amdgcn_cvt_pkrtz(p0, p1);
                    w[nt][p] = pk.i;
                }
            }

            // ---- C-layout -> P^T B-frags (cross-half dword exchange) ----
            // need: fc.w[0]={lh0:w0@lh0, lh1:w2@lh0}, fc.w[2]={lh0:w0@lh1, lh1:w2@lh1}
            // permlane32_swap(a,b): a.hi32 <-> b.lo32; returns {new_a, new_b}
            f16x8 pb[2][2];
#pragma unroll
            for (int nt = 0; nt < 2; nt++)
#pragma unroll
                for (int ks = 0; ks < 2; ks++) {
                    FragCast fc;
#if __has_builtin(__builtin_amdgcn_permlane32_swap)
                    v2i r02 = __builtin_amdgcn_permlane32_swap(w[nt][4*ks+0], w[nt][4*ks+2], false, false);
                    v2i r13 = __builtin_amdgcn_permlane32_swap(w[nt][4*ks+1], w[nt][4*ks+3], false, false);
                    fc.w[0] = r02.x; fc.w[1] = r13.x; fc.w[2] = r02.y; fc.w[3] = r13.y;
#else
                    int w0 = w[nt][4*ks], w1 = w[nt][4*ks+1], w2 = w[nt][4*ks+2], w3 = w[nt][4*ks+3];
                    fc.w[0] = lh ? __shfl_xor(w2, 32) : w0;
                    fc.w[1] = lh ? __shfl_xor(w3, 32) : w1;
                    fc.w[2] = lh ? w2 : __shfl_xor(w0, 32);
                    fc.w[3] = lh ? w3 : __shfl_xor(w1, 32);
#endif
                    pb[nt][ks] = fc.v;
                }

            // ---- O^T += V^T P^T (V frags shared across both n-tiles) ----
#pragma unroll
            for (int mt = 0; mt < 4; mt++)
#pragma unroll
                for (int ks = 0; ks < 2; ks++) {
                    f16x8 va = *(const f16x8*)(smc + 16384 + voff + kt * 8192 + ks * 4096 + mt * 512);
                    oacc[mt][0] = __builtin_amdgcn_mfma_f32_32x32x16_f16(va, pb[0][ks], oacc[mt][0], 0, 0, 0);
                    oacc[mt][1] = __builtin_amdgcn_mfma_f32_32x32x16_f16(va, pb[1][ks], oacc[mt][1], 0, 0, 0);
                }
        }
    }

    // ---- l across lane-halves ----
    float lt[2], linv[2];
#pragma unroll
    for (int nt = 0; nt < 2; nt++) {
        float l = lp[nt] + __shfl_xor(lp[nt], 32);
        lt[nt] = l;
        linv[nt] = (l > 0.f) ? 1.f / l : 0.f;
    }

    // ---- epilogue through per-wave LDS (swizzled) -> coalesced global ----
    __syncthreads();
    char* ob = (char*)smem + wv * 16384;
#pragma unroll
    for (int mt = 0; mt < 4; mt++)
#pragma unroll
        for (int nt = 0; nt < 2; nt++) {
            int qloc = l31 + 32 * nt;
#pragma unroll
            for (int g4 = 0; g4 < 4; g4++) {
                f16x4 hv;
#pragma unroll
                for (int r = 0; r < 4; r++) hv[r] = (f16)(oacc[mt][nt][g4 * 4 + r] * linv[nt]);
                int c16 = g4 + 4 * mt;
                *(f16x4*)(ob + qloc * 256 + ((c16 ^ (qloc & 7)) << 4) + lh * 8) = hv;
            }
        }
    __syncthreads();

    size_t obase = ((size_t)(c * NH + head) * SQPAD + qw) * HD;
#pragma unroll
    for (int a = 0; a < 4; a++)
#pragma unroll
        for (int b = 0; b < 4; b++) {
            int qloc = a * 16 + (lane >> 2);
            int c16  = (lane & 3) + 4 * b;
            f16x8 vv = *(const f16x8*)(ob + qloc * 256 + ((c16 ^ (qloc & 7)) << 4));
            *(f16x8*)(Opart + obase + (size_t)qloc * HD + c16 * 8) = vv;
        }

    if (lane < 32) {
        size_t lbase = (size_t)(c * NH + head) * SQPAD + qw;
        lpart[lbase + l31]      = lt[0];
        lpart[lbase + l31 + 32] = lt[1];
    }
}

// ============================================================
// Combine chunk partials -> AO f16 [S][DIM]
// ============================================================
__global__ __launch_bounds__(256) void combine(const f16* __restrict__ Opart,
                                               const float* __restrict__ lpart,
                                               f16* __restrict__ AO) {
    int gid = blockIdx.x * 256 + threadIdx.x;
    if (gid >= S_LEN * NH * 16) return;
    int dc = gid & 15;
    int head = (gid >> 4) % NH;
    int q = gid / (NH * 16);
    int tt = q >> 7;
    int qlast = min(tt * 128 + 127, S_LEN - 1);
    int nf = qlast / FRAME + 1;

    float sum[8] = {};
    float ls = 0.f;
    for (int c = 0; c < nf; c++) {
        float l = lpart[(size_t)(c * NH + head) * SQPAD + q];
        if (l > 0.f) {
            f16x8 o = *(const f16x8*)(Opart + ((size_t)(c * NH + head) * SQPAD + q) * HD + dc * 8);
#pragma unroll
            for (int j = 0; j < 8; j++) sum[j] += (float)o[j] * l;
            ls += l;
        }
    }
    float invl = 1.f / ls;
    f16x8 r;
#pragma unroll
    for (int j = 0; j < 8; j++) r[j] = (f16)(sum[j] * invl);
    *(f16x8*)(AO + (size_t)q * DIMSZ + head * HD + dc * 8) = r;
}

// ============================================================
// Output projection GEMM (m97 structure), f32 out
// ============================================================
__global__ __launch_bounds__(256) void gemm_lds(const f16* __restrict__ A,
                                                const f16* __restrict__ B,
                                                const float* __restrict__ bias,
                                                float* __restrict__ C) {
    __shared__ __align__(16) f16 Al[128 * 64];
    __shared__ __align__(16) f16 Bl[128 * 64];
    int tid = threadIdx.x;
    int lane = tid & 63, wv = tid >> 6;
    int l16 = lane & 15, quad = lane >> 4;
    int wr = (wv >> 1) * 64, wc = (wv & 1) * 64;
    int m0 = blockIdx.x * 128, n0 = blockIdx.y * 128;

    f32x4 acc[4][4] = {};

    for (int kb = 0; kb < DIMSZ; kb += 64) {
        __syncthreads();
#pragma unroll
        for (int j = 0; j < 4; j++) {
            int s = j * 256 + wv * 64 + lane;
            int r = s >> 3, cc = s & 7;
            const f16* src = A + (size_t)min(m0 + r, S_LEN - 1) * DIMSZ + kb + ((cc ^ (r & 7)) << 3);
            async16(src, (char*)Al + (j * 4096 + wv * 1024));
        }
#pragma unroll
        for (int j = 0; j < 4; j++) {
            int s = j * 256 + wv * 64 + lane;
            int r = s >> 3, cc = s & 7;
            const f16* src = B + (size_t)(n0 + r) * DIMSZ + kb + ((cc ^ (r & 7)) << 3);
            async16(src, (char*)Bl + (j * 4096 + wv * 1024));
        }
        __builtin_amdgcn_s_waitcnt(0x0f70);
        __syncthreads();

#pragma unroll
        for (int kc = 0; kc < 2; kc++) {
            f16x8 af[4], bf[4];
#pragma unroll
            for (int i = 0; i < 4; i++) {
                int ar = wr + i * 16 + l16;
                af[i] = *(const f16x8*)((const char*)Al + ar * 128 + (((kc * 4 + quad) ^ (ar & 7)) << 4));
                int br = wc + i * 16 + l16;
                bf[i] = *(const f16x8*)((const char*)Bl + br * 128 + (((kc * 4 + quad) ^ (br & 7)) << 4));
            }
#pragma unroll
            for (int mi = 0; mi < 4; mi++)
#pragma unroll
                for (int ni = 0; ni < 4; ni++)
                    acc[mi][ni] = __builtin_amdgcn_mfma_f32_16x16x32_f16(af[mi], bf[ni], acc[mi][ni], 0, 0, 0);
        }
    }

#pragma unroll
    for (int mi = 0; mi < 4; mi++)
#pragma unroll
        for (int ni = 0; ni < 4; ni++) {
            int col = n0 + wc + ni * 16 + l16;
            float bv = bias[col];
#pragma unroll
            for (int r = 0; r < 4; r++) {
                int row = m0 + wr + mi * 16 + quad * 4 + r;
                if (row < S_LEN) C[(size_t)row * DIMSZ + col] = acc[mi][ni][r] + bv;
            }
        }
}

// ============================================================
// host launch
// ============================================================
extern "C" void kernel_launch(void* const* d_in, const int* in_sizes, int n_in,
                              void* d_out, int out_size, void* d_ws, size_t ws_size,
                              hipStream_t stream) {
    const float* x     = (const float*)d_in[0];
    const float* freqs = (const float*)d_in[3];
    const float* Wq = (const float*)d_in[4];
    const float* bq = (const float*)d_in[5];
    const float* Wk = (const float*)d_in[6];
    const float* bk = (const float*)d_in[7];
    const float* Wv = (const float*)d_in[8];
    const float* bv = (const float*)d_in[9];
    const float* Wo = (const float*)d_in[10];
    const float* bo = (const float*)d_in[11];
    const float* gq = (const float*)d_in[12];
    const float* gk = (const float*)d_in[13];
    float* out = (float*)d_out;

    char* ws = (char*)d_ws;
    const size_t SZ_XH  = (size_t)S_LEN * DIMSZ * 2;     // 14,376,960
    const size_t SZ_W   = (size_t)DIMSZ * DIMSZ * 2;     //  4,718,592
    const size_t SZ_PAN = (size_t)NH * PANH * 2;         // 14,548,992
    const size_t SZ_OP  = (size_t)3 * NH * SQPAD * HD * 2;

    size_t off = 0;
    f16* xh   = (f16*)(ws + off); off += SZ_XH;
    f16* wqh  = (f16*)(ws + off); off += 4 * SZ_W;       // wq,wk,wv,wo contiguous
    f16* wkh  = wqh + (size_t)DIMSZ * DIMSZ;
    f16* wvh  = wkh + (size_t)DIMSZ * DIMSZ;
    f16* woh  = wvh + (size_t)DIMSZ * DIMSZ;
    f16* Qpan = (f16*)(ws + off); off += SZ_PAN;
    f16* Kpan = (f16*)(ws + off); off += SZ_PAN;
    f16* Vpan = (f16*)(ws + off); off += SZ_PAN;
    f16* AO   = (f16*)(ws + off); off += SZ_XH;
    // union: {preq, prek} (f16) before attention | {Opart, lpart} after
    f16*   preq  = (f16*)(ws + off);
    f16*   prek  = preq + (size_t)S_LEN * DIMSZ;
    f16*   Opart = (f16*)(ws + off);
    float* lpart = (float*)(ws + off + SZ_OP);

    cast_all<<<dim3(7020, 5), 256, 0, stream>>>(x, Wq, Wk, Wv, Wo, xh, wqh);

    gemm_qkv<<<dim3(37, 12, 3), 256, 0, stream>>>(xh, wqh, wkh, wvh, bq, bk, bv,
                                                  preq, prek, Vpan);

    norm_rope<<<dim3(S_LEN, 2), 256, 0, stream>>>(preq, prek, gq, gk, freqs, Qpan, Kpan);

    attn_part<<<dim3(75, 12), 128, 0, stream>>>(Qpan, Kpan, Vpan, Opart, lpart);
    combine<<<(S_LEN * NH * 16) / 256, 256, 0, stream>>>(Opart, lpart, AO);

    gemm_lds<<<dim3(37, 12), 256, 0, stream>>>(AO, woh, bo, out);
}

// Round 7
// 498.903 us; speedup vs baseline: 3.8418x; 1.0133x over previous
//
#include <hip/hip_runtime.h>
#include <hip/hip_bf16.h>
#include <math.h>
#include <stdint.h>

// ---- problem constants ----
#define S_LEN 4680
#define DIMSZ 1536
#define NH    12
#define HD    128
#define FRAME 1560
#define NGRP  74        // padded 64-key/-q groups (74*64 = 4736)
#define PANH  (NGRP * 8192)   // f16 elems per head in a panelized tensor
#define NSLOT 150       // (q-tile, chunk) slots per head: 12*2 + 12*4 + 13*6

typedef _Float16 f16;
typedef _Float16 f16x8 __attribute__((ext_vector_type(8)));
typedef _Float16 f16x4 __attribute__((ext_vector_type(4)));
typedef _Float16 f16x2 __attribute__((ext_vector_type(2)));
typedef __fp16   fp16x2 __attribute__((ext_vector_type(2)));
typedef float    f32x4  __attribute__((ext_vector_type(4)));
typedef float    f32x16 __attribute__((ext_vector_type(16)));
typedef int      v2i    __attribute__((ext_vector_type(2)));

__device__ __forceinline__ void async16(const void* g, void* l) {
    __builtin_amdgcn_global_load_lds((const __attribute__((address_space(1))) void*)g,
                                     (__attribute__((address_space(3))) void*)l, 16, 0, 0);
}

union PkCast { fp16x2 v; int i; };
union FragCast { int w[4]; f16x8 v; };

// ============================================================
// all f32->f16 casts in one dispatch: y=0 x, y=1..4 weights
// ============================================================
__global__ __launch_bounds__(256) void cast_all(const float* __restrict__ x,
                                                const float* __restrict__ wq,
                                                const float* __restrict__ wk,
                                                const float* __restrict__ wv,
                                                const float* __restrict__ wo,
                                                f16* __restrict__ xh,
                                                f16* __restrict__ wh) {
    int y = blockIdx.y;
    int i = blockIdx.x * 256 + threadIdx.x;
    if (y == 0) {
        if (i < (S_LEN * DIMSZ) / 4) {
            float4 v = ((const float4*)x)[i];
            f16x4 h; h[0]=(f16)v.x; h[1]=(f16)v.y; h[2]=(f16)v.z; h[3]=(f16)v.w;
            ((f16x4*)xh)[i] = h;
        }
    } else {
        const int nW4 = (DIMSZ * DIMSZ) / 4;
        if (i < nW4) {
            const float* src = (y==1)?wq:(y==2)?wk:(y==3)?wv:wo;
            float4 v = ((const float4*)src)[i];
            f16x4 h; h[0]=(f16)v.x; h[1]=(f16)v.y; h[2]=(f16)v.z; h[3]=(f16)v.w;
            ((f16x4*)wh)[(size_t)(y-1)*nW4 + i] = h;
        }
    }
}

// ============================================================
// Fused QKV GEMM (m97 structure), grid (37,12,3).
// z=0/1: pre-norm Q/K, f16 row-major. z=2: V, f16 panelized Vt.
// Vt panels: [head][key-group][8 kchunks][128 d][8 keys]
// ============================================================
__global__ __launch_bounds__(256) void gemm_qkv(const f16* __restrict__ A,
                                                const f16* __restrict__ Bq,
                                                const f16* __restrict__ Bk,
                                                const f16* __restrict__ Bv,
                                                const float* __restrict__ bq,
                                                const float* __restrict__ bk,
                                                const float* __restrict__ bv,
                                                f16* __restrict__ preq,
                                                f16* __restrict__ prek,
                                                f16* __restrict__ vtp) {
    int z = blockIdx.z;
    const f16* B = (z==0) ? Bq : (z==1) ? Bk : Bv;
    const float* bias = (z==0) ? bq : (z==1) ? bk : bv;

    __shared__ __align__(16) f16 Al[128 * 64];
    __shared__ __align__(16) f16 Bl[128 * 64];
    int tid = threadIdx.x;
    int lane = tid & 63, wv = tid >> 6;
    int l16 = lane & 15, quad = lane >> 4;
    int wr = (wv >> 1) * 64, wc = (wv & 1) * 64;
    int m0 = blockIdx.x * 128, n0 = blockIdx.y * 128;

    f32x4 acc[4][4] = {};

    for (int kb = 0; kb < DIMSZ; kb += 64) {
        __syncthreads();
#pragma unroll
        for (int j = 0; j < 4; j++) {
            int s = j * 256 + wv * 64 + lane;
            int r = s >> 3, cc = s & 7;
            const f16* src = A + (size_t)min(m0 + r, S_LEN - 1) * DIMSZ + kb + ((cc ^ (r & 7)) << 3);
            async16(src, (char*)Al + (j * 4096 + wv * 1024));
        }
#pragma unroll
        for (int j = 0; j < 4; j++) {
            int s = j * 256 + wv * 64 + lane;
            int r = s >> 3, cc = s & 7;
            const f16* src = B + (size_t)(n0 + r) * DIMSZ + kb + ((cc ^ (r & 7)) << 3);
            async16(src, (char*)Bl + (j * 4096 + wv * 1024));
        }
        __builtin_amdgcn_s_waitcnt(0x0f70);
        __syncthreads();

#pragma unroll
        for (int kc = 0; kc < 2; kc++) {
            f16x8 af[4], bf[4];
#pragma unroll
            for (int i = 0; i < 4; i++) {
                int ar = wr + i * 16 + l16;
                af[i] = *(const f16x8*)((const char*)Al + ar * 128 + (((kc * 4 + quad) ^ (ar & 7)) << 4));
                int br = wc + i * 16 + l16;
                bf[i] = *(const f16x8*)((const char*)Bl + br * 128 + (((kc * 4 + quad) ^ (br & 7)) << 4));
            }
#pragma unroll
            for (int mi = 0; mi < 4; mi++)
#pragma unroll
                for (int ni = 0; ni < 4; ni++)
                    acc[mi][ni] = __builtin_amdgcn_mfma_f32_16x16x32_f16(af[mi], bf[ni], acc[mi][ni], 0, 0, 0);
        }
    }

    if (z < 2) {
        f16* C = (z == 0) ? preq : prek;
#pragma unroll
        for (int mi = 0; mi < 4; mi++)
#pragma unroll
            for (int ni = 0; ni < 4; ni++) {
                int col = n0 + wc + ni * 16 + l16;
                float bv_ = bias[col];
#pragma unroll
                for (int r = 0; r < 4; r++) {
                    int row = m0 + wr + mi * 16 + quad * 4 + r;
                    if (row < S_LEN) C[(size_t)row * DIMSZ + col] = (f16)(acc[mi][ni][r] + bv_);
                }
            }
    } else {
#pragma unroll
        for (int mi = 0; mi < 4; mi++)
#pragma unroll
            for (int ni = 0; ni < 4; ni++) {
                int col  = n0 + wc + ni * 16 + l16;
                int vhead = col >> 7, d = col & 127;
                int base = m0 + wr + mi * 16 + quad * 4;   // 4 consecutive keys
                if (base < S_LEN) {
                    float bv_ = bias[col];
                    f16x4 h;
#pragma unroll
                    for (int r = 0; r < 4; r++) h[r] = (f16)(acc[mi][ni][r] + bv_);
                    size_t off = (size_t)vhead * PANH + (size_t)(base >> 6) * 8192
                               + ((base >> 3) & 7) * 1024 + d * 8 + (base & 7);
                    *(f16x4*)(vtp + off) = h;
                }
            }
    }
}

// ============================================================
// RMSNorm + RoPE -> panelized Q/K: [head][q-group][16 dchunks][64 q][8 d]
// grid (S_LEN, 2): y=0 Q, y=1 K
// ============================================================
__global__ __launch_bounds__(256) void norm_rope(const f16* __restrict__ preq,
                                                 const f16* __restrict__ prek,
                                                 const float* __restrict__ gq,
                                                 const float* __restrict__ gk,
                                                 const float* __restrict__ freqs,
                                                 f16* __restrict__ Qp,
                                                 f16* __restrict__ Kp) {
    int s = blockIdx.x, which = blockIdx.y;
    int t = threadIdx.x;
    const f16* pre = which ? prek : preq;
    const float* g = which ? gk : gq;
    f16* dst = which ? Kp : Qp;
    const f16* row = pre + (size_t)s * DIMSZ + t * 6;

    float v[6];
    float ss = 0.f;
#pragma unroll
    for (int i = 0; i < 3; i++) {
        f16x2 hp = *(const f16x2*)(row + 2 * i);
        v[2*i] = (float)hp[0]; v[2*i+1] = (float)hp[1];
        ss += v[2*i]*v[2*i] + v[2*i+1]*v[2*i+1];
    }
#pragma unroll
    for (int off = 32; off; off >>= 1) ss += __shfl_xor(ss, off);
    __shared__ float red[4];
    if ((t & 63) == 0) red[t >> 6] = ss;
    __syncthreads();
    float tot = red[0] + red[1] + red[2] + red[3];
    float rms = rsqrtf(tot * (1.0f / DIMSZ) + 1e-6f);

    int tpos = s / FRAME;
    int rem  = s % FRAME;
    int ypos = rem / 52;
    int xpos = s % 52;

#pragma unroll
    for (int u = 0; u < 3; u++) {
        int c = t * 6 + u * 2;
        int head = c >> 7;
        int d = c & 127;
        int j = d >> 1;
        int idx = (j < 22) ? tpos : ((j < 43) ? ypos : xpos);
        float ang = freqs[idx * 64 + j];
        float sn, cs;
        __sincosf(ang, &sn, &cs);
        float vr = v[u * 2]     * rms * g[c];
        float vi = v[u * 2 + 1] * rms * g[c + 1];
        f16* o = dst + (size_t)head * PANH + (size_t)(s >> 6) * 8192
               + (d >> 3) * 512 + (s & 63) * 8 + (d & 7);
        o[0] = (f16)(vr * cs - vi * sn);
        o[1] = (f16)(vr * sn + vi * cs);
    }
}

// ============================================================
// Attention partials. Block = 2 waves x 64 q (128 q-tile), head, chunk.
// Fine chunking: 2/4/6 chunks per tile by frame count -> grid (150, 12).
// 32x32x16 MFMA, S^T = K Q^T, O^T = V^T P^T.
// LDS = byte-image of panelized global groups -> conflict-free reads.
// ============================================================
__global__ __launch_bounds__(128, 2) void attn_part(const f16* __restrict__ Qp,
                                                    const f16* __restrict__ Kp,
                                                    const f16* __restrict__ Vp,
                                                    f16* __restrict__ Opart,
                                                    float* __restrict__ lpart) {
    int bx = blockIdx.x, head = blockIdx.y;
    int t, c, NC2;
    if (bx < 24)      { t = bx >> 1;             c = bx & 1;       NC2 = 2; }
    else if (bx < 72) { t = 12 + ((bx - 24) >> 2); c = (bx - 24) & 3; NC2 = 4; }
    else              { t = 24 + (bx - 72) / 6;  c = (bx - 72) % 6; NC2 = 6; }

    int qlast = min(t * 128 + 127, S_LEN - 1);
    int nfrm  = qlast / FRAME + 1;
    int kvend = nfrm * FRAME; if (kvend > S_LEN) kvend = S_LEN;
    int nG    = (kvend + 63) >> 6;
    int g0 = (c * nG) / NC2, g1 = ((c + 1) * nG) / NC2;
    int limB = ((t * 128) / FRAME + 1) * FRAME;

    int tid = threadIdx.x, lane = tid & 63, wv = tid >> 6;
    int l31 = lane & 31, lh = lane >> 5;
    int qw = t * 128 + wv * 64;

    __shared__ __align__(16) char smem[32768];
    const char* smc = smem;

    // Q B-frags from panelized global (coalesced), pre-scaled
    const f16* Qg = Qp + ((size_t)head * NGRP + (qw >> 6)) * 8192;
    f16x8 bqf[2][8];
#pragma unroll
    for (int nt = 0; nt < 2; nt++)
#pragma unroll
        for (int ks = 0; ks < 8; ks++) {
            f16x8 vq = *(const f16x8*)(Qg + (2 * ks + lh) * 512 + (l31 + 32 * nt) * 8);
            bqf[nt][ks] = vq * (f16)0.08838834764831845f;
        }

    int lim[2];
#pragma unroll
    for (int nt = 0; nt < 2; nt++) {
        int q = qw + l31 + 32 * nt;
        lim[nt] = (q / FRAME + 1) * FRAME;
    }

    f32x16 oacc[4][2] = {};
    float lp[2] = {0.f, 0.f};

    int koff = lh * 1024 + l31 * 16;
    int voff = lh * 2048 + l31 * 16;

    for (int g = g0; g < g1; g++) {
        int kb = g * 64;
        __syncthreads();
        const f16* Kg = Kp + ((size_t)head * NGRP + g) * 8192;
        const f16* Vg = Vp + ((size_t)head * NGRP + g) * 8192;
#pragma unroll
        for (int i = 0; i < 8; i++) {
            int s = i * 2 + wv;
            async16(Kg + s * 512 + lane * 8, (char*)smem + s * 1024 + lane * 16);
        }
#pragma unroll
        for (int i = 0; i < 8; i++) {
            int s = i * 2 + wv;
            async16(Vg + s * 512 + lane * 8, (char*)smem + 16384 + s * 1024 + lane * 16);
        }
        __builtin_amdgcn_s_waitcnt(0x0f70);   // vmcnt(0)
        __syncthreads();

        bool domask = (kb + 64 > limB);

#pragma unroll
        for (int kt = 0; kt < 2; kt++) {
            // ---- S^T = K Q^T ----
            f32x16 sc0 = {}, sc1 = {};
#pragma unroll
            for (int h = 0; h < 2; h++) {
                f16x8 ka[4];
#pragma unroll
                for (int i = 0; i < 4; i++)
                    ka[i] = *(const f16x8*)(smc + koff + (h * 4 + i) * 2048 + kt * 512);
#pragma unroll
                for (int i = 0; i < 4; i++) {
                    sc0 = __builtin_amdgcn_mfma_f32_32x32x16_f16(ka[i], bqf[0][h*4+i], sc0, 0, 0, 0);
                    sc1 = __builtin_amdgcn_mfma_f32_32x32x16_f16(ka[i], bqf[1][h*4+i], sc1, 0, 0, 0);
                }
            }

            // ---- mask + exp + pack ----
            int w[2][8];
            int keyb = kb + kt * 32 + 4 * lh;
#pragma unroll
            for (int nt = 0; nt < 2; nt++) {
#pragma unroll
                for (int p = 0; p < 8; p++) {
                    const int r0 = 2 * p;
                    float s0 = (nt == 0) ? sc0[r0]     : sc1[r0];
                    float s1 = (nt == 0) ? sc0[r0 + 1] : sc1[r0 + 1];
                    if (domask) {
                        int k0 = keyb + (r0 & 3) + 8 * (r0 >> 2);
                        if (k0     >= lim[nt]) s0 = -1e30f;
                        if (k0 + 1 >= lim[nt]) s1 = -1e30f;
                    }
                    float p0 = __expf(s0), p1 = __expf(s1);
                    lp[nt] += p0 + p1;
                    PkCast pk; pk.v = __builtin_amdgcn_cvt_pkrtz(p0, p1);
                    w[nt][p] = pk.i;
                }
            }

            // ---- C-layout -> P^T B-frags (cross-half dword exchange) ----
            f16x8 pb[2][2];
#pragma unroll
            for (int nt = 0; nt < 2; nt++)
#pragma unroll
                for (int ks = 0; ks < 2; ks++) {
                    FragCast fc;
#if __has_builtin(__builtin_amdgcn_permlane32_swap)
                    v2i r02 = __builtin_amdgcn_permlane32_swap(w[nt][4*ks+0], w[nt][4*ks+2], false, false);
                    v2i r13 = __builtin_amdgcn_permlane32_swap(w[nt][4*ks+1], w[nt][4*ks+3], false, false);
                    fc.w[0] = r02.x; fc.w[1] = r13.x; fc.w[2] = r02.y; fc.w[3] = r13.y;
#else
                    int w0 = w[nt][4*ks], w1 = w[nt][4*ks+1], w2 = w[nt][4*ks+2], w3 = w[nt][4*ks+3];
                    fc.w[0] = lh ? __shfl_xor(w2, 32) : w0;
                    fc.w[1] = lh ? __shfl_xor(w3, 32) : w1;
                    fc.w[2] = lh ? w2 : __shfl_xor(w0, 32);
                    fc.w[3] = lh ? w3 : __shfl_xor(w1, 32);
#endif
                    pb[nt][ks] = fc.v;
                }

            // ---- O^T += V^T P^T (V frags shared across both n-tiles) ----
#pragma unroll
            for (int mt = 0; mt < 4; mt++)
#pragma unroll
                for (int ks = 0; ks < 2; ks++) {
                    f16x8 va = *(const f16x8*)(smc + 16384 + voff + kt * 8192 + ks * 4096 + mt * 512);
                    oacc[mt][0] = __builtin_amdgcn_mfma_f32_32x32x16_f16(va, pb[0][ks], oacc[mt][0], 0, 0, 0);
                    oacc[mt][1] = __builtin_amdgcn_mfma_f32_32x32x16_f16(va, pb[1][ks], oacc[mt][1], 0, 0, 0);
                }
        }
    }

    // ---- l across lane-halves ----
    float lt[2], linv[2];
#pragma unroll
    for (int nt = 0; nt < 2; nt++) {
        float l = lp[nt] + __shfl_xor(lp[nt], 32);
        lt[nt] = l;
        linv[nt] = (l > 0.f) ? 1.f / l : 0.f;
    }

    // ---- epilogue through per-wave LDS (swizzled) -> coalesced global ----
    __syncthreads();
    char* ob = (char*)smem + wv * 16384;
#pragma unroll
    for (int mt = 0; mt < 4; mt++)
#pragma unroll
        for (int nt = 0; nt < 2; nt++) {
            int qloc = l31 + 32 * nt;
#pragma unroll
            for (int g4 = 0; g4 < 4; g4++) {
                f16x4 hv;
#pragma unroll
                for (int r = 0; r < 4; r++) hv[r] = (f16)(oacc[mt][nt][g4 * 4 + r] * linv[nt]);
                int c16 = g4 + 4 * mt;
                *(f16x4*)(ob + qloc * 256 + ((c16 ^ (qloc & 7)) << 4) + lh * 8) = hv;
            }
        }
    __syncthreads();

    // slot-compact partial layout: [head][slot=bx][128 q][128 d]
    size_t obase = ((size_t)(head * NSLOT + bx) * 128 + wv * 64) * HD;
#pragma unroll
    for (int a = 0; a < 4; a++)
#pragma unroll
        for (int b = 0; b < 4; b++) {
            int qloc = a * 16 + (lane >> 2);
            int c16  = (lane & 3) + 4 * b;
            f16x8 vv = *(const f16x8*)(ob + qloc * 256 + ((c16 ^ (qloc & 7)) << 4));
            *(f16x8*)(Opart + obase + (size_t)qloc * HD + c16 * 8) = vv;
        }

    if (lane < 32) {
        size_t lbase = (size_t)(head * NSLOT + bx) * 128 + wv * 64;
        lpart[lbase + l31]      = lt[0];
        lpart[lbase + l31 + 32] = lt[1];
    }
}

// ============================================================
// Combine chunk partials -> AO f16 [S][DIM]
// ============================================================
__global__ __launch_bounds__(256) void combine(const f16* __restrict__ Opart,
                                               const float* __restrict__ lpart,
                                               f16* __restrict__ AO) {
    int gid = blockIdx.x * 256 + threadIdx.x;
    if (gid >= S_LEN * NH * 16) return;
    int dc = gid & 15;
    int head = (gid >> 4) % NH;
    int q = gid / (NH * 16);
    int tt = q >> 7, qloc = q & 127;
    int base, nchunk;
    if (tt < 12)      { base = 2 * tt;             nchunk = 2; }
    else if (tt < 24) { base = 24 + 4 * (tt - 12); nchunk = 4; }
    else              { base = 72 + 6 * (tt - 24); nchunk = 6; }

    float sum[8] = {};
    float ls = 0.f;
    for (int c = 0; c < nchunk; c++) {
        size_t sbase = (size_t)(head * NSLOT + base + c) * 128 + qloc;
        float l = lpart[sbase];
        if (l > 0.f) {
            f16x8 o = *(const f16x8*)(Opart + sbase * HD + dc * 8);
#pragma unroll
            for (int j = 0; j < 8; j++) sum[j] += (float)o[j] * l;
            ls += l;
        }
    }
    float invl = 1.f / ls;
    f16x8 r;
#pragma unroll
    for (int j = 0; j < 8; j++) r[j] = (f16)(sum[j] * invl);
    *(f16x8*)(AO + (size_t)q * DIMSZ + head * HD + dc * 8) = r;
}

// ============================================================
// Output projection GEMM (m97 structure), f32 out
// ============================================================
__global__ __launch_bounds__(256) void gemm_lds(const f16* __restrict__ A,
                                                const f16* __restrict__ B,
                                                const float* __restrict__ bias,
                                                float* __restrict__ C) {
    __shared__ __align__(16) f16 Al[128 * 64];
    __shared__ __align__(16) f16 Bl[128 * 64];
    int tid = threadIdx.x;
    int lane = tid & 63, wv = tid >> 6;
    int l16 = lane & 15, quad = lane >> 4;
    int wr = (wv >> 1) * 64, wc = (wv & 1) * 64;
    int m0 = blockIdx.x * 128, n0 = blockIdx.y * 128;

    f32x4 acc[4][4] = {};

    for (int kb = 0; kb < DIMSZ; kb += 64) {
        __syncthreads();
#pragma unroll
        for (int j = 0; j < 4; j++) {
            int s = j * 256 + wv * 64 + lane;
            int r = s >> 3, cc = s & 7;
            const f16* src = A + (size_t)min(m0 + r, S_LEN - 1) * DIMSZ + kb + ((cc ^ (r & 7)) << 3);
            async16(src, (char*)Al + (j * 4096 + wv * 1024));
        }
#pragma unroll
        for (int j = 0; j < 4; j++) {
            int s = j * 256 + wv * 64 + lane;
            int r = s >> 3, cc = s & 7;
            const f16* src = B + (size_t)(n0 + r) * DIMSZ + kb + ((cc ^ (r & 7)) << 3);
            async16(src, (char*)Bl + (j * 4096 + wv * 1024));
        }
        __builtin_amdgcn_s_waitcnt(0x0f70);
        __syncthreads();

#pragma unroll
        for (int kc = 0; kc < 2; kc++) {
            f16x8 af[4], bf[4];
#pragma unroll
            for (int i = 0; i < 4; i++) {
                int ar = wr + i * 16 + l16;
                af[i] = *(const f16x8*)((const char*)Al + ar * 128 + (((kc * 4 + quad) ^ (ar & 7)) << 4));
                int br = wc + i * 16 + l16;
                bf[i] = *(const f16x8*)((const char*)Bl + br * 128 + (((kc * 4 + quad) ^ (br & 7)) << 4));
            }
#pragma unroll
            for (int mi = 0; mi < 4; mi++)
#pragma unroll
                for (int ni = 0; ni < 4; ni++)
                    acc[mi][ni] = __builtin_amdgcn_mfma_f32_16x16x32_f16(af[mi], bf[ni], acc[mi][ni], 0, 0, 0);
        }
    }

#pragma unroll
    for (int mi = 0; mi < 4; mi++)
#pragma unroll
        for (int ni = 0; ni < 4; ni++) {
            int col = n0 + wc + ni * 16 + l16;
            float bv = bias[col];
#pragma unroll
            for (int r = 0; r < 4; r++) {
                int row = m0 + wr + mi * 16 + quad * 4 + r;
                if (row < S_LEN) C[(size_t)row * DIMSZ + col] = acc[mi][ni][r] + bv;
            }
        }
}

// ============================================================
// host launch
// ============================================================
extern "C" void kernel_launch(void* const* d_in, const int* in_sizes, int n_in,
                              void* d_out, int out_size, void* d_ws, size_t ws_size,
                              hipStream_t stream) {
    const float* x     = (const float*)d_in[0];
    const float* freqs = (const float*)d_in[3];
    const float* Wq = (const float*)d_in[4];
    const float* bq = (const float*)d_in[5];
    const float* Wk = (const float*)d_in[6];
    const float* bk = (const float*)d_in[7];
    const float* Wv = (const float*)d_in[8];
    const float* bv = (const float*)d_in[9];
    const float* Wo = (const float*)d_in[10];
    const float* bo = (const float*)d_in[11];
    const float* gq = (const float*)d_in[12];
    const float* gk = (const float*)d_in[13];
    float* out = (float*)d_out;

    char* ws = (char*)d_ws;
    const size_t SZ_XH  = (size_t)S_LEN * DIMSZ * 2;     // 14,376,960
    const size_t SZ_W   = (size_t)DIMSZ * DIMSZ * 2;     //  4,718,592
    const size_t SZ_PAN = (size_t)NH * PANH * 2;         // 14,548,992
    const size_t SZ_OP  = (size_t)NH * NSLOT * 128 * HD * 2;  // 58,982,400

    size_t off = 0;
    f16* xh   = (f16*)(ws + off); off += SZ_XH;
    f16* wqh  = (f16*)(ws + off); off += 4 * SZ_W;       // wq,wk,wv,wo contiguous
    f16* wkh  = wqh + (size_t)DIMSZ * DIMSZ;
    f16* wvh  = wkh + (size_t)DIMSZ * DIMSZ;
    f16* woh  = wvh + (size_t)DIMSZ * DIMSZ;
    f16* Qpan = (f16*)(ws + off); off += SZ_PAN;
    f16* Kpan = (f16*)(ws + off); off += SZ_PAN;
    f16* Vpan = (f16*)(ws + off); off += SZ_PAN;
    f16* AO   = (f16*)(ws + off); off += SZ_XH;
    // union: {preq, prek} (f16) before attention | {Opart, lpart} after
    f16*   preq  = (f16*)(ws + off);
    f16*   prek  = preq + (size_t)S_LEN * DIMSZ;
    f16*   Opart = (f16*)(ws + off);
    float* lpart = (float*)(ws + off + SZ_OP);

    cast_all<<<dim3(7020, 5), 256, 0, stream>>>(x, Wq, Wk, Wv, Wo, xh, wqh);

    gemm_qkv<<<dim3(37, 12, 3), 256, 0, stream>>>(xh, wqh, wkh, wvh, bq, bk, bv,
                                                  preq, prek, Vpan);

    norm_rope<<<dim3(S_LEN, 2), 256, 0, stream>>>(preq, prek, gq, gk, freqs, Qpan, Kpan);

    attn_part<<<dim3(NSLOT, 12), 128, 0, stream>>>(Qpan, Kpan, Vpan, Opart, lpart);
    combine<<<(S_LEN * NH * 16 + 255) / 256, 256, 0, stream>>>(Opart, lpart, AO);

    gemm_lds<<<dim3(37, 12), 256, 0, stream>>>(AO, woh, bo, out);
}